// Round 1
// baseline (5311.816 us; speedup 1.0000x reference)
//
#include <hip/hip_runtime.h>
#include <hip/hip_bf16.h>
#include <cstdint>
#include <cstddef>

#define B_SZ    16
#define L_SZ    2048
#define DIN     64
#define DMODEL  512
#define DSTATE  16
#define NLAYERS 4
#define LN_EPS  1e-5f

// ---------------------------------------------------------------------------
// fp32 GEMM: C[M,N] = A[M,K] @ W[K,N] + bias[N], optional softplus epilogue.
// 128x128 block tile, 16 K-tile, 256 threads, 8x8 microtile.
// M % 128 == 0, N % 128 == 0, K % 16 == 0 (true for all shapes here).
// ---------------------------------------------------------------------------
template <int ACT>
__global__ __launch_bounds__(256) void gemm128(
    const float* __restrict__ A, const float* __restrict__ W,
    const float* __restrict__ bias, float* __restrict__ C,
    int M, int K, int N)
{
    constexpr int TM = 128, TN = 128, TK = 16, PAD = 4;
    __shared__ float As[TK][TM + PAD];   // transposed A tile
    __shared__ float Ws[TK][TN + PAD];

    const int tid = threadIdx.x;
    const int bm = blockIdx.x * TM;
    const int bn = blockIdx.y * TN;
    const int tx = tid & 15;   // n dir
    const int ty = tid >> 4;   // m dir

    float acc[8][8];
#pragma unroll
    for (int i = 0; i < 8; ++i)
#pragma unroll
        for (int j = 0; j < 8; ++j) acc[i][j] = 0.f;

    const int kl = tid & 15;   // A-load k index
    const int mb = tid >> 4;   // A-load m base
    const int nq = tid & 31;   // W-load float4 col
    const int kb = tid >> 5;   // W-load k base

    for (int k0 = 0; k0 < K; k0 += TK) {
        // A tile: 128x16, coalesced along k, stored transposed
#pragma unroll
        for (int i = 0; i < 8; ++i) {
            int ml = mb + i * 16;
            As[kl][ml] = A[(size_t)(bm + ml) * K + k0 + kl];
        }
        // W tile: 16x128, float4 loads/stores
#pragma unroll
        for (int i = 0; i < 2; ++i) {
            int kw = kb + i * 8;
            float4 wv = *reinterpret_cast<const float4*>(
                &W[(size_t)(k0 + kw) * N + bn + nq * 4]);
            *reinterpret_cast<float4*>(&Ws[kw][nq * 4]) = wv;
        }
        __syncthreads();
#pragma unroll
        for (int kk = 0; kk < TK; ++kk) {
            float4 a0 = *reinterpret_cast<const float4*>(&As[kk][ty * 8]);
            float4 a1 = *reinterpret_cast<const float4*>(&As[kk][ty * 8 + 4]);
            float4 w0 = *reinterpret_cast<const float4*>(&Ws[kk][tx * 8]);
            float4 w1 = *reinterpret_cast<const float4*>(&Ws[kk][tx * 8 + 4]);
            float a[8] = {a0.x, a0.y, a0.z, a0.w, a1.x, a1.y, a1.z, a1.w};
            float w[8] = {w0.x, w0.y, w0.z, w0.w, w1.x, w1.y, w1.z, w1.w};
#pragma unroll
            for (int i = 0; i < 8; ++i)
#pragma unroll
                for (int j = 0; j < 8; ++j)
                    acc[i][j] = fmaf(a[i], w[j], acc[i][j]);
        }
        __syncthreads();
    }
#pragma unroll
    for (int i = 0; i < 8; ++i) {
        size_t rowo = (size_t)(bm + ty * 8 + i) * N + bn + tx * 8;
#pragma unroll
        for (int j = 0; j < 8; ++j) {
            float v = acc[i][j] + bias[bn + tx * 8 + j];
            if (ACT == 1) v = (v > 20.f) ? v : log1pf(__expf(v));  // softplus
            C[rowo + j] = v;
        }
    }
}

// ---------------------------------------------------------------------------
// Fused B/C projection: Bo[M,16] = A[M,512]@WB, Co = A@WC. 16 m x 16 n /block.
// ---------------------------------------------------------------------------
__global__ __launch_bounds__(256) void gemm_bc(
    const float* __restrict__ A, const float* __restrict__ WB,
    const float* __restrict__ WC, float* __restrict__ Bo, float* __restrict__ Co)
{
    const int tid = threadIdx.x;
    const int n = tid & 15;
    const int ml = tid >> 4;
    const size_t m = (size_t)blockIdx.x * 16 + ml;
    const float4* arow4 = reinterpret_cast<const float4*>(A + m * DMODEL);
    float accB = 0.f, accC = 0.f;
#pragma unroll 4
    for (int kq = 0; kq < DMODEL / 4; ++kq) {
        float4 a4 = arow4[kq];
        int k = kq * 4;
        accB = fmaf(a4.x, WB[(k + 0) * DSTATE + n], accB);
        accB = fmaf(a4.y, WB[(k + 1) * DSTATE + n], accB);
        accB = fmaf(a4.z, WB[(k + 2) * DSTATE + n], accB);
        accB = fmaf(a4.w, WB[(k + 3) * DSTATE + n], accB);
        accC = fmaf(a4.x, WC[(k + 0) * DSTATE + n], accC);
        accC = fmaf(a4.y, WC[(k + 1) * DSTATE + n], accC);
        accC = fmaf(a4.z, WC[(k + 2) * DSTATE + n], accC);
        accC = fmaf(a4.w, WC[(k + 3) * DSTATE + n], accC);
    }
    Bo[m * DSTATE + n] = accB;
    Co[m * DSTATE + n] = accC;
}

// ---------------------------------------------------------------------------
// Selective scan. thread=(d,n): h in register, sequential over t.
// block = 16 d x 16 n; grid = (DMODEL/16, B).
// y[b,t,d] = sum_n h[t] * C[b,t,n]  + u*Dskip
// ---------------------------------------------------------------------------
__global__ __launch_bounds__(256) void scan_kernel(
    const float* __restrict__ u, const float* __restrict__ dt,
    const float* __restrict__ Bm, const float* __restrict__ Cm,
    const float* __restrict__ A_log, const float* __restrict__ Dskip,
    float* __restrict__ y)
{
    const int b = blockIdx.y;
    const int tid = threadIdx.x;
    const int n = tid & 15;
    const int dl = tid >> 4;
    const int d = blockIdx.x * 16 + dl;

    const float Ac = -__expf(A_log[d * DSTATE + n]);
    const float Dk = Dskip[d];

    size_t base_d = ((size_t)b * L_SZ) * DMODEL + d;
    size_t base_n = ((size_t)b * L_SZ) * DSTATE + n;

    float h = 0.f;
#pragma unroll 4
    for (int t = 0; t < L_SZ; ++t) {
        float dtv = dt[base_d + (size_t)t * DMODEL];
        float uv  = u [base_d + (size_t)t * DMODEL];
        float Bv  = Bm[base_n + (size_t)t * DSTATE];
        float Cv  = Cm[base_n + (size_t)t * DSTATE];
        float dA = __expf(dtv * Ac);
        h = fmaf(dA, h, dtv * uv * Bv);
        float p = h * Cv;
        p += __shfl_xor(p, 8);
        p += __shfl_xor(p, 4);
        p += __shfl_xor(p, 2);
        p += __shfl_xor(p, 1);
        if (n == 0) y[base_d + (size_t)t * DMODEL] = fmaf(uv, Dk, p);
    }
}

// ---------------------------------------------------------------------------
// LayerNorm(last token) + head dot product. One block per batch.
// ---------------------------------------------------------------------------
__global__ __launch_bounds__(256) void ln_head_kernel(
    const float* __restrict__ yb, const float* __restrict__ g,
    const float* __restrict__ bb, const float* __restrict__ hw,
    const float* __restrict__ hb, float* __restrict__ out)
{
    const int b = blockIdx.x;
    const int tid = threadIdx.x;
    const float* row = yb + ((size_t)b * L_SZ + (L_SZ - 1)) * DMODEL;
    float v0 = row[tid], v1 = row[tid + 256];
    float s = v0 + v1;
    float s2 = v0 * v0 + v1 * v1;
#pragma unroll
    for (int o = 32; o >= 1; o >>= 1) {
        s += __shfl_xor(s, o);
        s2 += __shfl_xor(s2, o);
    }
    __shared__ float red[8];
    const int w = tid >> 6;
    if ((tid & 63) == 0) { red[w] = s; red[4 + w] = s2; }
    __syncthreads();
    s = red[0] + red[1] + red[2] + red[3];
    s2 = red[4] + red[5] + red[6] + red[7];
    float mu = s * (1.f / DMODEL);
    float var = s2 * (1.f / DMODEL) - mu * mu;
    float r = rsqrtf(var + LN_EPS);
    float c = ((v0 - mu) * r * g[tid] + bb[tid]) * hw[tid]
            + ((v1 - mu) * r * g[tid + 256] + bb[tid + 256]) * hw[tid + 256];
#pragma unroll
    for (int o = 32; o >= 1; o >>= 1) c += __shfl_xor(c, o);
    __syncthreads();
    if ((tid & 63) == 0) red[w] = c;
    __syncthreads();
    if (tid == 0) out[b] = red[0] + red[1] + red[2] + red[3] + hb[0];
}

// ---------------------------------------------------------------------------
extern "C" void kernel_launch(void* const* d_in, const int* in_sizes, int n_in,
                              void* d_out, int out_size, void* d_ws, size_t ws_size,
                              hipStream_t stream)
{
    const float* x      = (const float*)d_in[0];
    const float* W_in0  = (const float*)d_in[1];
    const float* b_in0  = (const float*)d_in[2];
    const float* W_in   = (const float*)d_in[3];
    const float* b_in   = (const float*)d_in[4];
    const float* A_log  = (const float*)d_in[5];
    const float* D_skip = (const float*)d_in[6];
    const float* W_dt   = (const float*)d_in[7];
    const float* b_dt   = (const float*)d_in[8];
    const float* W_B    = (const float*)d_in[9];
    const float* W_C    = (const float*)d_in[10];
    const float* ln_g   = (const float*)d_in[11];
    const float* ln_b   = (const float*)d_in[12];
    const float* head_w = (const float*)d_in[13];
    const float* head_b = (const float*)d_in[14];
    float* out = (float*)d_out;

    const size_t BLD = (size_t)B_SZ * L_SZ * DMODEL;     // 16.78M elems
    const size_t BLN = (size_t)B_SZ * L_SZ * DSTATE;
    float* ybuf  = (float*)d_ws;         // also next layer's input; X dead after u-GEMM
    float* ubuf  = ybuf + BLD;
    float* dtbuf = ubuf + BLD;
    float* Bbuf  = dtbuf + BLD;
    float* Cbuf  = Bbuf + BLN;

    const int M = B_SZ * L_SZ;           // 32768
    const float* X = x;
    int K = DIN;
    const float* Wl = W_in0;
    const float* bl = b_in0;

    for (int l = 0; l < NLAYERS; ++l) {
        gemm128<0><<<dim3(M / 128, DMODEL / 128), 256, 0, stream>>>(
            X, Wl, bl, ubuf, M, K, DMODEL);
        gemm128<1><<<dim3(M / 128, DMODEL / 128), 256, 0, stream>>>(
            ubuf, W_dt + (size_t)l * DMODEL * DMODEL, b_dt + l * DMODEL,
            dtbuf, M, DMODEL, DMODEL);
        gemm_bc<<<M / 16, 256, 0, stream>>>(
            ubuf, W_B + (size_t)l * DMODEL * DSTATE,
            W_C + (size_t)l * DMODEL * DSTATE, Bbuf, Cbuf);
        scan_kernel<<<dim3(DMODEL / 16, B_SZ), 256, 0, stream>>>(
            ubuf, dtbuf, Bbuf, Cbuf,
            A_log + (size_t)l * DMODEL * DSTATE, D_skip + l * DMODEL, ybuf);
        X = ybuf;
        K = DMODEL;
        Wl = W_in + (size_t)l * DMODEL * DMODEL;
        bl = b_in + (size_t)l * DMODEL;
    }

    ln_head_kernel<<<B_SZ, 256, 0, stream>>>(ybuf, ln_g, ln_b, head_w, head_b, out);
}

// Round 2
// 3321.756 us; speedup vs baseline: 1.5991x; 1.5991x over previous
//
#include <hip/hip_runtime.h>
#include <hip/hip_bf16.h>
#include <cstdint>
#include <cstddef>

#define B_SZ    16
#define L_SZ    2048
#define DIN     64
#define DMODEL  512
#define DSTATE  16
#define NLAYERS 4
#define LN_EPS  1e-5f
#define NC      8            // chunks along L
#define TCH     (L_SZ / NC)  // 256 steps per chunk

// ---------------------------------------------------------------------------
// fp32 GEMM: C[M,N] = A[M,K] @ W[K,N] + bias[N], optional softplus epilogue.
// 128x128 block tile, 16 K-tile, 256 threads, 8x8 microtile.
// ---------------------------------------------------------------------------
template <int ACT>
__global__ __launch_bounds__(256) void gemm128(
    const float* __restrict__ A, const float* __restrict__ W,
    const float* __restrict__ bias, float* __restrict__ C,
    int M, int K, int N)
{
    constexpr int TM = 128, TN = 128, TK = 16, PAD = 4;
    __shared__ float As[TK][TM + PAD];   // transposed A tile
    __shared__ float Ws[TK][TN + PAD];

    const int tid = threadIdx.x;
    const int bm = blockIdx.x * TM;
    const int bn = blockIdx.y * TN;
    const int tx = tid & 15;   // n dir
    const int ty = tid >> 4;   // m dir

    float acc[8][8];
#pragma unroll
    for (int i = 0; i < 8; ++i)
#pragma unroll
        for (int j = 0; j < 8; ++j) acc[i][j] = 0.f;

    const int kl = tid & 15;   // A-load k index
    const int mb = tid >> 4;   // A-load m base
    const int nq = tid & 31;   // W-load float4 col
    const int kb = tid >> 5;   // W-load k base

    for (int k0 = 0; k0 < K; k0 += TK) {
#pragma unroll
        for (int i = 0; i < 8; ++i) {
            int ml = mb + i * 16;
            As[kl][ml] = A[(size_t)(bm + ml) * K + k0 + kl];
        }
#pragma unroll
        for (int i = 0; i < 2; ++i) {
            int kw = kb + i * 8;
            float4 wv = *reinterpret_cast<const float4*>(
                &W[(size_t)(k0 + kw) * N + bn + nq * 4]);
            *reinterpret_cast<float4*>(&Ws[kw][nq * 4]) = wv;
        }
        __syncthreads();
#pragma unroll
        for (int kk = 0; kk < TK; ++kk) {
            float4 a0 = *reinterpret_cast<const float4*>(&As[kk][ty * 8]);
            float4 a1 = *reinterpret_cast<const float4*>(&As[kk][ty * 8 + 4]);
            float4 w0 = *reinterpret_cast<const float4*>(&Ws[kk][tx * 8]);
            float4 w1 = *reinterpret_cast<const float4*>(&Ws[kk][tx * 8 + 4]);
            float a[8] = {a0.x, a0.y, a0.z, a0.w, a1.x, a1.y, a1.z, a1.w};
            float w[8] = {w0.x, w0.y, w0.z, w0.w, w1.x, w1.y, w1.z, w1.w};
#pragma unroll
            for (int i = 0; i < 8; ++i)
#pragma unroll
                for (int j = 0; j < 8; ++j)
                    acc[i][j] = fmaf(a[i], w[j], acc[i][j]);
        }
        __syncthreads();
    }
#pragma unroll
    for (int i = 0; i < 8; ++i) {
        size_t rowo = (size_t)(bm + ty * 8 + i) * N + bn + tx * 8;
#pragma unroll
        for (int j = 0; j < 8; ++j) {
            float v = acc[i][j] + bias[bn + tx * 8 + j];
            if (ACT == 1) v = (v > 20.f) ? v : log1pf(__expf(v));  // softplus
            C[rowo + j] = v;
        }
    }
}

// ---------------------------------------------------------------------------
// Fused B/C projection: Bo[M,16] = A[M,512]@WB, Co = A@WC. 16 m x 16 n /block.
// ---------------------------------------------------------------------------
__global__ __launch_bounds__(256) void gemm_bc(
    const float* __restrict__ A, const float* __restrict__ WB,
    const float* __restrict__ WC, float* __restrict__ Bo, float* __restrict__ Co)
{
    const int tid = threadIdx.x;
    const int n = tid & 15;
    const int ml = tid >> 4;
    const size_t m = (size_t)blockIdx.x * 16 + ml;
    const float4* arow4 = reinterpret_cast<const float4*>(A + m * DMODEL);
    float accB = 0.f, accC = 0.f;
#pragma unroll 4
    for (int kq = 0; kq < DMODEL / 4; ++kq) {
        float4 a4 = arow4[kq];
        int k = kq * 4;
        accB = fmaf(a4.x, WB[(k + 0) * DSTATE + n], accB);
        accB = fmaf(a4.y, WB[(k + 1) * DSTATE + n], accB);
        accB = fmaf(a4.z, WB[(k + 2) * DSTATE + n], accB);
        accB = fmaf(a4.w, WB[(k + 3) * DSTATE + n], accB);
        accC = fmaf(a4.x, WC[(k + 0) * DSTATE + n], accC);
        accC = fmaf(a4.y, WC[(k + 1) * DSTATE + n], accC);
        accC = fmaf(a4.z, WC[(k + 2) * DSTATE + n], accC);
        accC = fmaf(a4.w, WC[(k + 3) * DSTATE + n], accC);
    }
    Bo[m * DSTATE + n] = accB;
    Co[m * DSTATE + n] = accC;
}

// ---------------------------------------------------------------------------
// Chunked selective scan, pass 1: per (b, chunk, d, n) compute
//   P = prod_{t in chunk} exp(dt*A)      (chunk decay)
//   S = chunk-local scan end state       (h starting from 0)
// block = 16 d x 16 n, grid = (D/16, NC, B)
// ---------------------------------------------------------------------------
__global__ __launch_bounds__(256) void scan_pass1(
    const float* __restrict__ u, const float* __restrict__ dt,
    const float* __restrict__ Bm, const float* __restrict__ A_log,
    float* __restrict__ P, float* __restrict__ S)
{
    const int b = blockIdx.z, c = blockIdx.y;
    const int tid = threadIdx.x;
    const int n = tid & 15;
    const int dl = tid >> 4;
    const int d = blockIdx.x * 16 + dl;

    const float Ac = -__expf(A_log[d * DSTATE + n]);
    size_t base_d = ((size_t)b * L_SZ + (size_t)c * TCH) * DMODEL + d;
    size_t base_n = ((size_t)b * L_SZ + (size_t)c * TCH) * DSTATE + n;

    float p = 1.f, s = 0.f;
#pragma unroll 4
    for (int t = 0; t < TCH; ++t) {
        float dtv = dt[base_d + (size_t)t * DMODEL];
        float uv  = u [base_d + (size_t)t * DMODEL];
        float Bv  = Bm[base_n + (size_t)t * DSTATE];
        float a = __expf(dtv * Ac);
        p *= a;
        s = fmaf(a, s, dtv * uv * Bv);
    }
    size_t o = (((size_t)b * NC + c) * DMODEL + d) * DSTATE + n;
    P[o] = p;
    S[o] = s;
}

// ---------------------------------------------------------------------------
// Chunk fix-up: sequential scan over the NC chunk states per (b,d,n).
// H0[b,c,d,n] = h entering chunk c.
// ---------------------------------------------------------------------------
__global__ __launch_bounds__(256) void scan_fix(
    const float* __restrict__ P, const float* __restrict__ S,
    float* __restrict__ H0)
{
    const int idx = blockIdx.x * 256 + threadIdx.x;   // over B*D*N
    const int dn = idx & (DMODEL * DSTATE - 1);
    const int b = idx >> 13;                          // D*N = 8192
    float h = 0.f;
#pragma unroll
    for (int c = 0; c < NC; ++c) {
        size_t o = (((size_t)b * NC + c) << 13) + dn;
        H0[o] = h;
        h = fmaf(P[o], h, S[o]);
    }
}

// ---------------------------------------------------------------------------
// Pass 2: redo chunk scan seeded with H0, emit y.
// ---------------------------------------------------------------------------
__global__ __launch_bounds__(256) void scan_pass2(
    const float* __restrict__ u, const float* __restrict__ dt,
    const float* __restrict__ Bm, const float* __restrict__ Cm,
    const float* __restrict__ A_log, const float* __restrict__ Dskip,
    const float* __restrict__ H0, float* __restrict__ y)
{
    const int b = blockIdx.z, c = blockIdx.y;
    const int tid = threadIdx.x;
    const int n = tid & 15;
    const int dl = tid >> 4;
    const int d = blockIdx.x * 16 + dl;

    const float Ac = -__expf(A_log[d * DSTATE + n]);
    const float Dk = Dskip[d];
    size_t base_d = ((size_t)b * L_SZ + (size_t)c * TCH) * DMODEL + d;
    size_t base_n = ((size_t)b * L_SZ + (size_t)c * TCH) * DSTATE + n;

    float h = H0[(((size_t)b * NC + c) * DMODEL + d) * DSTATE + n];
#pragma unroll 4
    for (int t = 0; t < TCH; ++t) {
        float dtv = dt[base_d + (size_t)t * DMODEL];
        float uv  = u [base_d + (size_t)t * DMODEL];
        float Bv  = Bm[base_n + (size_t)t * DSTATE];
        float Cv  = Cm[base_n + (size_t)t * DSTATE];
        float a = __expf(dtv * Ac);
        h = fmaf(a, h, dtv * uv * Bv);
        float p = h * Cv;
        p += __shfl_xor(p, 8);
        p += __shfl_xor(p, 4);
        p += __shfl_xor(p, 2);
        p += __shfl_xor(p, 1);
        if (n == 0) y[base_d + (size_t)t * DMODEL] = fmaf(uv, Dk, p);
    }
}

// ---------------------------------------------------------------------------
// LayerNorm(last token) + head dot product. One block per batch.
// ---------------------------------------------------------------------------
__global__ __launch_bounds__(256) void ln_head_kernel(
    const float* __restrict__ yb, const float* __restrict__ g,
    const float* __restrict__ bb, const float* __restrict__ hw,
    const float* __restrict__ hb, float* __restrict__ out)
{
    const int b = blockIdx.x;
    const int tid = threadIdx.x;
    const float* row = yb + ((size_t)b * L_SZ + (L_SZ - 1)) * DMODEL;
    float v0 = row[tid], v1 = row[tid + 256];
    float s = v0 + v1;
    float s2 = v0 * v0 + v1 * v1;
#pragma unroll
    for (int o = 32; o >= 1; o >>= 1) {
        s += __shfl_xor(s, o);
        s2 += __shfl_xor(s2, o);
    }
    __shared__ float red[8];
    const int w = tid >> 6;
    if ((tid & 63) == 0) { red[w] = s; red[4 + w] = s2; }
    __syncthreads();
    s = red[0] + red[1] + red[2] + red[3];
    s2 = red[4] + red[5] + red[6] + red[7];
    float mu = s * (1.f / DMODEL);
    float var = s2 * (1.f / DMODEL) - mu * mu;
    float r = rsqrtf(var + LN_EPS);
    float c = ((v0 - mu) * r * g[tid] + bb[tid]) * hw[tid]
            + ((v1 - mu) * r * g[tid + 256] + bb[tid + 256]) * hw[tid + 256];
#pragma unroll
    for (int o = 32; o >= 1; o >>= 1) c += __shfl_xor(c, o);
    __syncthreads();
    if ((tid & 63) == 0) red[w] = c;
    __syncthreads();
    if (tid == 0) out[b] = red[0] + red[1] + red[2] + red[3] + hb[0];
}

// ---------------------------------------------------------------------------
extern "C" void kernel_launch(void* const* d_in, const int* in_sizes, int n_in,
                              void* d_out, int out_size, void* d_ws, size_t ws_size,
                              hipStream_t stream)
{
    const float* x      = (const float*)d_in[0];
    const float* W_in0  = (const float*)d_in[1];
    const float* b_in0  = (const float*)d_in[2];
    const float* W_in   = (const float*)d_in[3];
    const float* b_in   = (const float*)d_in[4];
    const float* A_log  = (const float*)d_in[5];
    const float* D_skip = (const float*)d_in[6];
    const float* W_dt   = (const float*)d_in[7];
    const float* b_dt   = (const float*)d_in[8];
    const float* W_B    = (const float*)d_in[9];
    const float* W_C    = (const float*)d_in[10];
    const float* ln_g   = (const float*)d_in[11];
    const float* ln_b   = (const float*)d_in[12];
    const float* head_w = (const float*)d_in[13];
    const float* head_b = (const float*)d_in[14];
    float* out = (float*)d_out;

    const size_t BLD = (size_t)B_SZ * L_SZ * DMODEL;     // 16.78M elems
    const size_t BLN = (size_t)B_SZ * L_SZ * DSTATE;
    const size_t BCD = (size_t)B_SZ * NC * DMODEL * DSTATE;  // 1M elems
    float* ybuf  = (float*)d_ws;         // also next layer's input
    float* ubuf  = ybuf + BLD;
    float* dtbuf = ubuf + BLD;
    float* Bbuf  = dtbuf + BLD;
    float* Cbuf  = Bbuf + BLN;
    float* Pbuf  = Cbuf + BLN;
    float* Sbuf  = Pbuf + BCD;
    float* H0buf = Sbuf + BCD;

    const int M = B_SZ * L_SZ;           // 32768
    const float* X = x;
    int K = DIN;
    const float* Wl = W_in0;
    const float* bl = b_in0;

    for (int l = 0; l < NLAYERS; ++l) {
        gemm128<0><<<dim3(M / 128, DMODEL / 128), 256, 0, stream>>>(
            X, Wl, bl, ubuf, M, K, DMODEL);
        gemm128<1><<<dim3(M / 128, DMODEL / 128), 256, 0, stream>>>(
            ubuf, W_dt + (size_t)l * DMODEL * DMODEL, b_dt + l * DMODEL,
            dtbuf, M, DMODEL, DMODEL);
        gemm_bc<<<M / 16, 256, 0, stream>>>(
            ubuf, W_B + (size_t)l * DMODEL * DSTATE,
            W_C + (size_t)l * DMODEL * DSTATE, Bbuf, Cbuf);
        const float* Al = A_log + (size_t)l * DMODEL * DSTATE;
        scan_pass1<<<dim3(DMODEL / 16, NC, B_SZ), 256, 0, stream>>>(
            ubuf, dtbuf, Bbuf, Al, Pbuf, Sbuf);
        scan_fix<<<(B_SZ * DMODEL * DSTATE) / 256, 256, 0, stream>>>(
            Pbuf, Sbuf, H0buf);
        scan_pass2<<<dim3(DMODEL / 16, NC, B_SZ), 256, 0, stream>>>(
            ubuf, dtbuf, Bbuf, Cbuf, Al, D_skip + l * DMODEL, H0buf, ybuf);
        X = ybuf;
        K = DMODEL;
        Wl = W_in + (size_t)l * DMODEL * DMODEL;
        bl = b_in + (size_t)l * DMODEL;
    }

    ln_head_kernel<<<B_SZ, 256, 0, stream>>>(ybuf, ln_g, ln_b, head_w, head_b, out);
}

// Round 4
// 1221.279 us; speedup vs baseline: 4.3494x; 2.7199x over previous
//
#include <hip/hip_runtime.h>
#include <hip/hip_bf16.h>
#include <cstdint>
#include <cstddef>

#define B_SZ    16
#define L_SZ    2048
#define DIN     64
#define DMODEL  512
#define DSTATE  16
#define NLAYERS 4
#define LN_EPS  1e-5f
#define NC      16
#define TCH     (L_SZ / NC)   // 128

typedef __bf16 bf16x8 __attribute__((ext_vector_type(8)));
typedef float  f32x4  __attribute__((ext_vector_type(4)));
typedef unsigned short u16;
typedef unsigned int   u32;

__device__ __forceinline__ u16 f2bf(float f) {
    u32 u = __builtin_bit_cast(u32, f);
    u += 0x7fffu + ((u >> 16) & 1u);
    return (u16)(u >> 16);
}
__device__ __forceinline__ float bf2f(u16 v) {
    u32 u = ((u32)v) << 16;
    return __builtin_bit_cast(float, u);
}

__device__ __forceinline__ void gload16(const void* g, void* l) {
    __builtin_amdgcn_global_load_lds(
        (__attribute__((address_space(1))) void*)(g),
        (__attribute__((address_space(3))) void*)(l), 16, 0, 0);
}

// ---------------------------------------------------------------------------
// bf16 MFMA GEMM: A[M,K](bf16) @ BT[N,K]^T(bf16) + bias.
// 128x128 tile, BK=64, 4 waves (2x2), wave tile 64x64 = 4x4 frags 16x16x32.
// LDS via global_load_lds(16B), pre-swizzled global source, swizzled reads.
// ACT=1: softplus. OUT: 0=f32 only, 1=f32+bf16, 2=bf16 only.
// ---------------------------------------------------------------------------
template <int ACT, int OUT>
__global__ __launch_bounds__(256) void gemm_mfma(
    const u16* __restrict__ A, const u16* __restrict__ BT,
    const float* __restrict__ bias, float* __restrict__ C,
    u16* __restrict__ Cb, int M, int K, int N)
{
    constexpr int BM = 128, BK = 64;
    __shared__ u16 As[BM * BK];
    __shared__ u16 Bs[BM * BK];

    const int tid = threadIdx.x;
    const int wv = tid >> 6, ln = tid & 63;
    const int bm = blockIdx.x * BM, bn = blockIdx.y * BM;
    const int wm = (wv >> 1) * 64, wn = (wv & 1) * 64;

    f32x4 acc[4][4];
#pragma unroll
    for (int i = 0; i < 4; ++i)
#pragma unroll
        for (int j = 0; j < 4; ++j) acc[i][j] = (f32x4){0.f, 0.f, 0.f, 0.f};

    for (int k0 = 0; k0 < K; k0 += BK) {
#pragma unroll
        for (int i = 0; i < 4; ++i) {
            int t = i * 256 + tid;
            int m = t >> 3, s = t & 7;
            int ksrc = (s ^ (m & 7)) * 8;           // pre-swizzled source chunk
            gload16(A + (size_t)(bm + m) * K + k0 + ksrc,
                    &As[(i * 256 + wv * 64) * 8]);
            gload16(BT + (size_t)(bn + m) * K + k0 + ksrc,
                    &Bs[(i * 256 + wv * 64) * 8]);
        }
        __syncthreads();
#pragma unroll
        for (int ks = 0; ks < 2; ++ks) {
            bf16x8 af[4], bfr[4];
            const int g = ln >> 4, lm = ln & 15;
            const int c = ks * 4 + g;
#pragma unroll
            for (int f = 0; f < 4; ++f) {
                int ml = wm + f * 16 + lm;
                af[f] = *(const bf16x8*)&As[ml * 64 + ((c ^ (ml & 7)) * 8)];
                int nl = wn + f * 16 + lm;
                bfr[f] = *(const bf16x8*)&Bs[nl * 64 + ((c ^ (nl & 7)) * 8)];
            }
#pragma unroll
            for (int fm = 0; fm < 4; ++fm)
#pragma unroll
                for (int fn = 0; fn < 4; ++fn)
                    acc[fm][fn] = __builtin_amdgcn_mfma_f32_16x16x32_bf16(
                        af[fm], bfr[fn], acc[fm][fn], 0, 0, 0);
        }
        __syncthreads();
    }

    // C/D layout: col=lane&15, row=(lane>>4)*4+reg  [verified m89/m91]
    const int cg = ln >> 4, lc = ln & 15;
#pragma unroll
    for (int fm = 0; fm < 4; ++fm) {
#pragma unroll
        for (int fn = 0; fn < 4; ++fn) {
            int col = bn + wn + fn * 16 + lc;
            float bv = bias[col];
#pragma unroll
            for (int r = 0; r < 4; ++r) {
                int row = bm + wm + fm * 16 + cg * 4 + r;
                float v = acc[fm][fn][r] + bv;
                if (ACT == 1) v = (v > 20.f) ? v : log1pf(__expf(v));
                size_t o = (size_t)row * N + col;
                if (OUT != 2) C[o] = v;
                if (OUT >= 1) Cb[o] = f2bf(v);
            }
        }
    }
}

// ---------------------------------------------------------------------------
// Weight transpose + cast: WT[N][K] (bf16) from W[K][N] (f32). 32x32 tiles.
// ---------------------------------------------------------------------------
__global__ __launch_bounds__(256) void wtrans(
    const float* __restrict__ W, u16* __restrict__ WT, int K, int N)
{
    __shared__ float tile[32][33];
    const float* Wm = W + (size_t)blockIdx.z * K * N;
    u16* WTm = WT + (size_t)blockIdx.z * K * N;
    int k0 = blockIdx.x * 32, n0 = blockIdx.y * 32;
    int tx = threadIdx.x & 31, ty = threadIdx.x >> 5;
#pragma unroll
    for (int i = 0; i < 4; ++i)
        tile[ty + 8 * i][tx] = Wm[(size_t)(k0 + ty + 8 * i) * N + n0 + tx];
    __syncthreads();
#pragma unroll
    for (int i = 0; i < 4; ++i)
        WTm[(size_t)(n0 + ty + 8 * i) * K + k0 + tx] = f2bf(tile[tx][ty + 8 * i]);
}

// x -> bf16 cast
__global__ __launch_bounds__(256) void castx(
    const float* __restrict__ x, u16* __restrict__ xb, int n4)
{
    int i = blockIdx.x * 256 + threadIdx.x;
    if (i < n4) {
        float4 v = ((const float4*)x)[i];
        ushort4 o;
        o.x = f2bf(v.x); o.y = f2bf(v.y); o.z = f2bf(v.z); o.w = f2bf(v.w);
        ((ushort4*)xb)[i] = o;
    }
}

// ---------------------------------------------------------------------------
// Fused B/C projection from bf16 u: Bo[M,16] = u@WB, Co = u@WC (f32 out).
// ---------------------------------------------------------------------------
__global__ __launch_bounds__(256) void gemm_bc(
    const u16* __restrict__ A, const float* __restrict__ WB,
    const float* __restrict__ WC, float* __restrict__ Bo, float* __restrict__ Co)
{
    const int tid = threadIdx.x;
    const int n = tid & 15;
    const int ml = tid >> 4;
    const size_t m = (size_t)blockIdx.x * 16 + ml;
    const uint4* arow = reinterpret_cast<const uint4*>(A + m * DMODEL);
    float accB = 0.f, accC = 0.f;
#pragma unroll 2
    for (int kq = 0; kq < DMODEL / 8; ++kq) {
        uint4 q = arow[kq];
        float a[8];
        a[0] = __builtin_bit_cast(float, q.x << 16);
        a[1] = __builtin_bit_cast(float, q.x & 0xffff0000u);
        a[2] = __builtin_bit_cast(float, q.y << 16);
        a[3] = __builtin_bit_cast(float, q.y & 0xffff0000u);
        a[4] = __builtin_bit_cast(float, q.z << 16);
        a[5] = __builtin_bit_cast(float, q.z & 0xffff0000u);
        a[6] = __builtin_bit_cast(float, q.w << 16);
        a[7] = __builtin_bit_cast(float, q.w & 0xffff0000u);
        int k = kq * 8;
#pragma unroll
        for (int j = 0; j < 8; ++j) {
            accB = fmaf(a[j], WB[(k + j) * DSTATE + n], accB);
            accC = fmaf(a[j], WC[(k + j) * DSTATE + n], accC);
        }
    }
    Bo[m * DSTATE + n] = accB;
    Co[m * DSTATE + n] = accC;
}

// ---------------------------------------------------------------------------
// Scan pass 1: thread = one d, h[n] in regs. B-chunk staged in LDS.
// ---------------------------------------------------------------------------
__global__ __launch_bounds__(256) void scan_pass1(
    const u16* __restrict__ u, const u16* __restrict__ dt,
    const float* __restrict__ Bm, const float* __restrict__ A_log,
    float* __restrict__ P, float* __restrict__ S)
{
    const int tid = threadIdx.x;
    const int d = blockIdx.x * 256 + tid;
    const int c = blockIdx.y, b = blockIdx.z;
    __shared__ float Bs[TCH][DSTATE];

    const float* Bsrc = Bm + ((size_t)b * L_SZ + (size_t)c * TCH) * DSTATE;
    for (int i = tid; i < TCH * DSTATE / 4; i += 256)
        ((float4*)Bs)[i] = ((const float4*)Bsrc)[i];

    float Ac[16];
#pragma unroll
    for (int n = 0; n < 16; ++n) Ac[n] = -__expf(A_log[d * DSTATE + n]);
    __syncthreads();

    float p[16], s[16];
#pragma unroll
    for (int n = 0; n < 16; ++n) { p[n] = 1.f; s[n] = 0.f; }

    const size_t base = ((size_t)b * L_SZ + (size_t)c * TCH) * DMODEL + d;
#pragma unroll 2
    for (int t = 0; t < TCH; ++t) {
        float dtv = bf2f(dt[base + (size_t)t * DMODEL]);
        float uv  = bf2f(u [base + (size_t)t * DMODEL]);
        float du = dtv * uv;
#pragma unroll
        for (int n = 0; n < 16; ++n) {
            float a = __expf(dtv * Ac[n]);
            p[n] *= a;
            s[n] = fmaf(a, s[n], du * Bs[t][n]);
        }
    }
    size_t o = (((size_t)b * NC + c) * DMODEL + d) * DSTATE;
#pragma unroll
    for (int n = 0; n < 16; ++n) { P[o + n] = p[n]; S[o + n] = s[n]; }
}

// ---------------------------------------------------------------------------
// Chunk fix-up: sequential over NC chunks per (b,d,n).
// ---------------------------------------------------------------------------
__global__ __launch_bounds__(256) void scan_fix(
    const float* __restrict__ P, const float* __restrict__ S,
    float* __restrict__ H0)
{
    const int idx = blockIdx.x * 256 + threadIdx.x;   // over B*D*N
    const int dn = idx & (DMODEL * DSTATE - 1);
    const int b = idx >> 13;                          // D*N = 8192
    float h = 0.f;
#pragma unroll
    for (int c = 0; c < NC; ++c) {
        size_t o = (((size_t)b * NC + c) << 13) + dn;
        H0[o] = h;
        h = fmaf(P[o], h, S[o]);
    }
}

// ---------------------------------------------------------------------------
// Scan pass 2: seeded with H0; emit y as bf16 (+ fp32 last-token row).
// ---------------------------------------------------------------------------
__global__ __launch_bounds__(256) void scan_pass2(
    const u16* __restrict__ u, const u16* __restrict__ dt,
    const float* __restrict__ Bm, const float* __restrict__ Cm,
    const float* __restrict__ A_log, const float* __restrict__ Dskip,
    const float* __restrict__ H0, u16* __restrict__ yb,
    float* __restrict__ ylast)
{
    const int tid = threadIdx.x;
    const int d = blockIdx.x * 256 + tid;
    const int c = blockIdx.y, b = blockIdx.z;
    __shared__ float Bs[TCH][DSTATE];
    __shared__ float Cs[TCH][DSTATE];

    const float* Bsrc = Bm + ((size_t)b * L_SZ + (size_t)c * TCH) * DSTATE;
    const float* Csrc = Cm + ((size_t)b * L_SZ + (size_t)c * TCH) * DSTATE;
    for (int i = tid; i < TCH * DSTATE / 4; i += 256) {
        ((float4*)Bs)[i] = ((const float4*)Bsrc)[i];
        ((float4*)Cs)[i] = ((const float4*)Csrc)[i];
    }

    float Ac[16];
#pragma unroll
    for (int n = 0; n < 16; ++n) Ac[n] = -__expf(A_log[d * DSTATE + n]);
    const float Dk = Dskip[d];

    float h[16];
    size_t ho = (((size_t)b * NC + c) * DMODEL + d) * DSTATE;
#pragma unroll
    for (int n = 0; n < 16; ++n) h[n] = H0[ho + n];
    __syncthreads();

    const size_t base = ((size_t)b * L_SZ + (size_t)c * TCH) * DMODEL + d;
#pragma unroll 2
    for (int t = 0; t < TCH; ++t) {
        float dtv = bf2f(dt[base + (size_t)t * DMODEL]);
        float uv  = bf2f(u [base + (size_t)t * DMODEL]);
        float du = dtv * uv;
        float yv = 0.f;
#pragma unroll
        for (int n = 0; n < 16; ++n) {
            float a = __expf(dtv * Ac[n]);
            h[n] = fmaf(a, h[n], du * Bs[t][n]);
            yv = fmaf(h[n], Cs[t][n], yv);
        }
        yv = fmaf(uv, Dk, yv);
        yb[base + (size_t)t * DMODEL] = f2bf(yv);
        if (c == NC - 1 && t == TCH - 1) ylast[(size_t)b * DMODEL + d] = yv;
    }
}

// ---------------------------------------------------------------------------
// LayerNorm(last token) + head. One block per batch.
// ---------------------------------------------------------------------------
__global__ __launch_bounds__(256) void ln_head_kernel(
    const float* __restrict__ ylast, const float* __restrict__ g,
    const float* __restrict__ bb, const float* __restrict__ hw,
    const float* __restrict__ hb, float* __restrict__ out)
{
    const int b = blockIdx.x;
    const int tid = threadIdx.x;
    const float* row = ylast + (size_t)b * DMODEL;
    float v0 = row[tid], v1 = row[tid + 256];
    float s = v0 + v1;
    float s2 = v0 * v0 + v1 * v1;
#pragma unroll
    for (int o = 32; o >= 1; o >>= 1) {
        s += __shfl_xor(s, o);
        s2 += __shfl_xor(s2, o);
    }
    __shared__ float red[8];
    const int w = tid >> 6;
    if ((tid & 63) == 0) { red[w] = s; red[4 + w] = s2; }
    __syncthreads();
    s = red[0] + red[1] + red[2] + red[3];
    s2 = red[4] + red[5] + red[6] + red[7];
    float mu = s * (1.f / DMODEL);
    float var = s2 * (1.f / DMODEL) - mu * mu;
    float r = rsqrtf(var + LN_EPS);
    float c = ((v0 - mu) * r * g[tid] + bb[tid]) * hw[tid]
            + ((v1 - mu) * r * g[tid + 256] + bb[tid + 256]) * hw[tid + 256];
#pragma unroll
    for (int o = 32; o >= 1; o >>= 1) c += __shfl_xor(c, o);
    __syncthreads();
    if ((tid & 63) == 0) red[w] = c;
    __syncthreads();
    if (tid == 0) out[b] = red[0] + red[1] + red[2] + red[3] + hb[0];
}

// ---------------------------------------------------------------------------
extern "C" void kernel_launch(void* const* d_in, const int* in_sizes, int n_in,
                              void* d_out, int out_size, void* d_ws, size_t ws_size,
                              hipStream_t stream)
{
    const float* x      = (const float*)d_in[0];
    const float* W_in0  = (const float*)d_in[1];
    const float* b_in0  = (const float*)d_in[2];
    const float* W_in   = (const float*)d_in[3];
    const float* b_in   = (const float*)d_in[4];
    const float* A_log  = (const float*)d_in[5];
    const float* D_skip = (const float*)d_in[6];
    const float* W_dt   = (const float*)d_in[7];
    const float* b_dt   = (const float*)d_in[8];
    const float* W_B    = (const float*)d_in[9];
    const float* W_C    = (const float*)d_in[10];
    const float* ln_g   = (const float*)d_in[11];
    const float* ln_b   = (const float*)d_in[12];
    const float* head_w = (const float*)d_in[13];
    const float* head_b = (const float*)d_in[14];
    float* out = (float*)d_out;

    const size_t BLD = (size_t)B_SZ * L_SZ * DMODEL;         // 16.78M
    const size_t BLN = (size_t)B_SZ * L_SZ * DSTATE;         // 0.52M
    const size_t BCD = (size_t)B_SZ * NC * DMODEL * DSTATE;  // 2.10M
    const size_t XBN = (size_t)B_SZ * L_SZ * DIN;            // 2.10M

    // fp32 region (~29.4 MB), then bf16 region (~108.6 MB); total ~138 MB
    float* fp = (float*)d_ws;
    float* Bbuf  = fp; fp += BLN;
    float* Cbuf  = fp; fp += BLN;
    float* Pbuf  = fp; fp += BCD;
    float* Sbuf  = fp; fp += BCD;
    float* H0buf = fp; fp += BCD;
    float* ylast = fp; fp += (size_t)B_SZ * DMODEL;
    u16* hp = (u16*)fp;
    u16* xb   = hp; hp += XBN;
    u16* ub   = hp; hp += BLD;   // u bf16
    u16* dtb  = hp; hp += BLD;   // dt bf16
    u16* ybuf = hp; hp += BLD;   // layer output bf16 (next layer input)
    u16* WT0  = hp; hp += (size_t)DIN * DMODEL;
    u16* WTin = hp; hp += (size_t)(NLAYERS - 1) * DMODEL * DMODEL;
    u16* WTdt = hp; hp += (size_t)NLAYERS * DMODEL * DMODEL;

    const int M = B_SZ * L_SZ;   // 32768

    castx<<<(XBN / 4 + 255) / 256, 256, 0, stream>>>(x, xb, XBN / 4);
    wtrans<<<dim3(DIN / 32, DMODEL / 32, 1), 256, 0, stream>>>(W_in0, WT0, DIN, DMODEL);
    wtrans<<<dim3(DMODEL / 32, DMODEL / 32, NLAYERS - 1), 256, 0, stream>>>(W_in, WTin, DMODEL, DMODEL);
    wtrans<<<dim3(DMODEL / 32, DMODEL / 32, NLAYERS), 256, 0, stream>>>(W_dt, WTdt, DMODEL, DMODEL);

    for (int l = 0; l < NLAYERS; ++l) {
        const u16* Ab = (l == 0) ? xb : ybuf;
        int K = (l == 0) ? DIN : DMODEL;
        const u16* WTu = (l == 0) ? WT0 : WTin + (size_t)(l - 1) * DMODEL * DMODEL;
        const float* bu = (l == 0) ? b_in0 : b_in + (size_t)(l - 1) * DMODEL;

        gemm_mfma<0, 2><<<dim3(M / 128, DMODEL / 128), 256, 0, stream>>>(
            Ab, WTu, bu, (float*)nullptr, ub, M, K, DMODEL);
        gemm_mfma<1, 2><<<dim3(M / 128, DMODEL / 128), 256, 0, stream>>>(
            ub, WTdt + (size_t)l * DMODEL * DMODEL, b_dt + (size_t)l * DMODEL,
            (float*)nullptr, dtb, M, DMODEL, DMODEL);
        gemm_bc<<<M / 16, 256, 0, stream>>>(
            ub, W_B + (size_t)l * DMODEL * DSTATE,
            W_C + (size_t)l * DMODEL * DSTATE, Bbuf, Cbuf);
        const float* Al = A_log + (size_t)l * DMODEL * DSTATE;
        scan_pass1<<<dim3(DMODEL / 256, NC, B_SZ), 256, 0, stream>>>(
            ub, dtb, Bbuf, Al, Pbuf, Sbuf);
        scan_fix<<<(B_SZ * DMODEL * DSTATE) / 256, 256, 0, stream>>>(
            Pbuf, Sbuf, H0buf);
        scan_pass2<<<dim3(DMODEL / 256, NC, B_SZ), 256, 0, stream>>>(
            ub, dtb, Bbuf, Cbuf, Al, D_skip + (size_t)l * DMODEL,
            H0buf, ybuf, ylast);
    }

    ln_head_kernel<<<B_SZ, 256, 0, stream>>>(ylast, ln_g, ln_b, head_w, head_b, out);
}

// Round 5
// 1150.665 us; speedup vs baseline: 4.6163x; 1.0614x over previous
//
#include <hip/hip_runtime.h>
#include <hip/hip_bf16.h>
#include <cstdint>
#include <cstddef>

#define B_SZ    16
#define L_SZ    2048
#define DIN     64
#define DMODEL  512
#define DSTATE  16
#define NLAYERS 4
#define LN_EPS  1e-5f
#define NC      16
#define TCH     (L_SZ / NC)   // 128

typedef __bf16 bf16x8 __attribute__((ext_vector_type(8)));
typedef float  f32x4  __attribute__((ext_vector_type(4)));
typedef unsigned short u16;
typedef unsigned int   u32;

__device__ __forceinline__ u16 f2bf(float f) {
    u32 u = __builtin_bit_cast(u32, f);
    u += 0x7fffu + ((u >> 16) & 1u);
    return (u16)(u >> 16);
}
__device__ __forceinline__ float bf2f(u16 v) {
    u32 u = ((u32)v) << 16;
    return __builtin_bit_cast(float, u);
}

__device__ __forceinline__ void gload16(const void* g, void* l) {
    __builtin_amdgcn_global_load_lds(
        (__attribute__((address_space(1))) void*)(g),
        (__attribute__((address_space(3))) void*)(l), 16, 0, 0);
}

// ---------------------------------------------------------------------------
// bf16 MFMA GEMM, double-buffered counted-vmcnt pipeline (T3-lite).
// A[M,K](bf16) @ BT[N,K]^T(bf16) + bias. 128x128 tile, BK=64, 4 waves.
// K is a template param (NT=K/64 fully unrolled) so waitcnt immediates are
// per-iteration constants. Loads for tile k+1 stay in flight across the
// barriers while tile k computes (never vmcnt(0) until the last tile).
// ACT=1: softplus. OUT: 2=bf16 only.
// ---------------------------------------------------------------------------
template <int ACT, int OUT, int K>
__global__ __launch_bounds__(256) void gemm_mfma(
    const u16* __restrict__ A, const u16* __restrict__ BT,
    const float* __restrict__ bias, float* __restrict__ C,
    u16* __restrict__ Cb, int M, int N)
{
    constexpr int BM = 128, BK = 64;
    constexpr int NT = K / BK;
    __shared__ u16 As[2][BM * BK];   // 2 x 16 KB
    __shared__ u16 Bs[2][BM * BK];   // 2 x 16 KB  (total 64 KB)

    const int tid = threadIdx.x;
    const int wv = tid >> 6, ln = tid & 63;
    const int bm = blockIdx.x * BM, bn = blockIdx.y * BM;
    const int wm = (wv >> 1) * 64, wn = (wv & 1) * 64;

    f32x4 acc[4][4];
#pragma unroll
    for (int i = 0; i < 4; ++i)
#pragma unroll
        for (int j = 0; j < 4; ++j) acc[i][j] = (f32x4){0.f, 0.f, 0.f, 0.f};

    // stage one 128x64 A-tile + B-tile into buffer `buf` (8 wave-instrs)
    auto stage = [&](int buf, int k0) {
#pragma unroll
        for (int i = 0; i < 4; ++i) {
            int t = i * 256 + tid;
            int m = t >> 3, s = t & 7;
            int ksrc = (s ^ (m & 7)) * 8;           // pre-swizzled source chunk
            gload16(A + (size_t)(bm + m) * K + k0 + ksrc,
                    &As[buf][(i * 256 + wv * 64) * 8]);
            gload16(BT + (size_t)(bn + m) * K + k0 + ksrc,
                    &Bs[buf][(i * 256 + wv * 64) * 8]);
        }
    };

    // prologue: tiles 0 and 1 in flight (16 outstanding loads per wave)
    stage(0, 0);
    if (NT > 1) stage(1, BK);

#pragma unroll
    for (int kt = 0; kt < NT; ++kt) {
        // retire exactly tile kt's 8 loads; keep tile kt+1 in flight
        if (kt == NT - 1) asm volatile("s_waitcnt vmcnt(0)" ::: "memory");
        else              asm volatile("s_waitcnt vmcnt(8)" ::: "memory");
        __builtin_amdgcn_s_barrier();

        const int buf = kt & 1;
#pragma unroll
        for (int ks = 0; ks < 2; ++ks) {
            bf16x8 af[4], bfr[4];
            const int g = ln >> 4, lm = ln & 15;
            const int c = ks * 4 + g;
#pragma unroll
            for (int f = 0; f < 4; ++f) {
                int ml = wm + f * 16 + lm;
                af[f] = *(const bf16x8*)&As[buf][ml * 64 + ((c ^ (ml & 7)) * 8)];
                int nl = wn + f * 16 + lm;
                bfr[f] = *(const bf16x8*)&Bs[buf][nl * 64 + ((c ^ (nl & 7)) * 8)];
            }
#pragma unroll
            for (int fm = 0; fm < 4; ++fm)
#pragma unroll
                for (int fn = 0; fn < 4; ++fn)
                    acc[fm][fn] = __builtin_amdgcn_mfma_f32_16x16x32_bf16(
                        af[fm], bfr[fn], acc[fm][fn], 0, 0, 0);
        }

        // all waves done reading buf -> safe to restage it
        asm volatile("s_waitcnt lgkmcnt(0)" ::: "memory");
        __builtin_amdgcn_s_barrier();
        if (kt + 2 < NT) stage(buf, (kt + 2) * BK);
    }

    // C/D layout: col=lane&15, row=(lane>>4)*4+reg  [verified m89/m91]
    const int cg = ln >> 4, lc = ln & 15;
#pragma unroll
    for (int fm = 0; fm < 4; ++fm) {
#pragma unroll
        for (int fn = 0; fn < 4; ++fn) {
            int col = bn + wn + fn * 16 + lc;
            float bv = bias[col];
#pragma unroll
            for (int r = 0; r < 4; ++r) {
                int row = bm + wm + fm * 16 + cg * 4 + r;
                float v = acc[fm][fn][r] + bv;
                if (ACT == 1) v = (v > 20.f) ? v : __logf(1.f + __expf(v));
                size_t o = (size_t)row * N + col;
                if (OUT != 2) C[o] = v;
                if (OUT >= 1) Cb[o] = f2bf(v);
            }
        }
    }
}

// ---------------------------------------------------------------------------
// Weight transpose + cast: WT[N][K] (bf16) from W[K][N] (f32). 32x32 tiles.
// ---------------------------------------------------------------------------
__global__ __launch_bounds__(256) void wtrans(
    const float* __restrict__ W, u16* __restrict__ WT, int K, int N)
{
    __shared__ float tile[32][33];
    const float* Wm = W + (size_t)blockIdx.z * K * N;
    u16* WTm = WT + (size_t)blockIdx.z * K * N;
    int k0 = blockIdx.x * 32, n0 = blockIdx.y * 32;
    int tx = threadIdx.x & 31, ty = threadIdx.x >> 5;
#pragma unroll
    for (int i = 0; i < 4; ++i)
        tile[ty + 8 * i][tx] = Wm[(size_t)(k0 + ty + 8 * i) * N + n0 + tx];
    __syncthreads();
#pragma unroll
    for (int i = 0; i < 4; ++i)
        WTm[(size_t)(n0 + ty + 8 * i) * K + k0 + tx] = f2bf(tile[tx][ty + 8 * i]);
}

// x -> bf16 cast
__global__ __launch_bounds__(256) void castx(
    const float* __restrict__ x, u16* __restrict__ xb, int n4)
{
    int i = blockIdx.x * 256 + threadIdx.x;
    if (i < n4) {
        float4 v = ((const float4*)x)[i];
        ushort4 o;
        o.x = f2bf(v.x); o.y = f2bf(v.y); o.z = f2bf(v.z); o.w = f2bf(v.w);
        ((ushort4*)xb)[i] = o;
    }
}

// ---------------------------------------------------------------------------
// Fused B/C projection from bf16 u: Bo[M,16] = u@WB, Co = u@WC (f32 out).
// ---------------------------------------------------------------------------
__global__ __launch_bounds__(256) void gemm_bc(
    const u16* __restrict__ A, const float* __restrict__ WB,
    const float* __restrict__ WC, float* __restrict__ Bo, float* __restrict__ Co)
{
    const int tid = threadIdx.x;
    const int n = tid & 15;
    const int ml = tid >> 4;
    const size_t m = (size_t)blockIdx.x * 16 + ml;
    const uint4* arow = reinterpret_cast<const uint4*>(A + m * DMODEL);
    float accB = 0.f, accC = 0.f;
#pragma unroll 2
    for (int kq = 0; kq < DMODEL / 8; ++kq) {
        uint4 q = arow[kq];
        float a[8];
        a[0] = __builtin_bit_cast(float, q.x << 16);
        a[1] = __builtin_bit_cast(float, q.x & 0xffff0000u);
        a[2] = __builtin_bit_cast(float, q.y << 16);
        a[3] = __builtin_bit_cast(float, q.y & 0xffff0000u);
        a[4] = __builtin_bit_cast(float, q.z << 16);
        a[5] = __builtin_bit_cast(float, q.z & 0xffff0000u);
        a[6] = __builtin_bit_cast(float, q.w << 16);
        a[7] = __builtin_bit_cast(float, q.w & 0xffff0000u);
        int k = kq * 8;
#pragma unroll
        for (int j = 0; j < 8; ++j) {
            accB = fmaf(a[j], WB[(k + j) * DSTATE + n], accB);
            accC = fmaf(a[j], WC[(k + j) * DSTATE + n], accC);
        }
    }
    Bo[m * DSTATE + n] = accB;
    Co[m * DSTATE + n] = accC;
}

// ---------------------------------------------------------------------------
// Scan pass 1: thread = one d, h[n] in regs. B-chunk staged in LDS.
// ---------------------------------------------------------------------------
__global__ __launch_bounds__(256) void scan_pass1(
    const u16* __restrict__ u, const u16* __restrict__ dt,
    const float* __restrict__ Bm, const float* __restrict__ A_log,
    float* __restrict__ P, float* __restrict__ S)
{
    const int tid = threadIdx.x;
    const int d = blockIdx.x * 256 + tid;
    const int c = blockIdx.y, b = blockIdx.z;
    __shared__ float Bs[TCH][DSTATE];

    const float* Bsrc = Bm + ((size_t)b * L_SZ + (size_t)c * TCH) * DSTATE;
    for (int i = tid; i < TCH * DSTATE / 4; i += 256)
        ((float4*)Bs)[i] = ((const float4*)Bsrc)[i];

    float Ac[16];
#pragma unroll
    for (int n = 0; n < 16; ++n) Ac[n] = -__expf(A_log[d * DSTATE + n]);
    __syncthreads();

    float p[16], s[16];
#pragma unroll
    for (int n = 0; n < 16; ++n) { p[n] = 1.f; s[n] = 0.f; }

    const size_t base = ((size_t)b * L_SZ + (size_t)c * TCH) * DMODEL + d;
#pragma unroll 2
    for (int t = 0; t < TCH; ++t) {
        float dtv = bf2f(dt[base + (size_t)t * DMODEL]);
        float uv  = bf2f(u [base + (size_t)t * DMODEL]);
        float du = dtv * uv;
#pragma unroll
        for (int n = 0; n < 16; ++n) {
            float a = __expf(dtv * Ac[n]);
            p[n] *= a;
            s[n] = fmaf(a, s[n], du * Bs[t][n]);
        }
    }
    size_t o = (((size_t)b * NC + c) * DMODEL + d) * DSTATE;
#pragma unroll
    for (int n = 0; n < 16; ++n) { P[o + n] = p[n]; S[o + n] = s[n]; }
}

// ---------------------------------------------------------------------------
// Chunk fix-up: sequential over NC chunks per (b,d,n).
// ---------------------------------------------------------------------------
__global__ __launch_bounds__(256) void scan_fix(
    const float* __restrict__ P, const float* __restrict__ S,
    float* __restrict__ H0)
{
    const int idx = blockIdx.x * 256 + threadIdx.x;   // over B*D*N
    const int dn = idx & (DMODEL * DSTATE - 1);
    const int b = idx >> 13;                          // D*N = 8192
    float h = 0.f;
#pragma unroll
    for (int c = 0; c < NC; ++c) {
        size_t o = (((size_t)b * NC + c) << 13) + dn;
        H0[o] = h;
        h = fmaf(P[o], h, S[o]);
    }
}

// ---------------------------------------------------------------------------
// Scan pass 2: seeded with H0; emit y as bf16 (+ fp32 last-token row).
// ---------------------------------------------------------------------------
__global__ __launch_bounds__(256) void scan_pass2(
    const u16* __restrict__ u, const u16* __restrict__ dt,
    const float* __restrict__ Bm, const float* __restrict__ Cm,
    const float* __restrict__ A_log, const float* __restrict__ Dskip,
    const float* __restrict__ H0, u16* __restrict__ yb,
    float* __restrict__ ylast)
{
    const int tid = threadIdx.x;
    const int d = blockIdx.x * 256 + tid;
    const int c = blockIdx.y, b = blockIdx.z;
    __shared__ float Bs[TCH][DSTATE];
    __shared__ float Cs[TCH][DSTATE];

    const float* Bsrc = Bm + ((size_t)b * L_SZ + (size_t)c * TCH) * DSTATE;
    const float* Csrc = Cm + ((size_t)b * L_SZ + (size_t)c * TCH) * DSTATE;
    for (int i = tid; i < TCH * DSTATE / 4; i += 256) {
        ((float4*)Bs)[i] = ((const float4*)Bsrc)[i];
        ((float4*)Cs)[i] = ((const float4*)Csrc)[i];
    }

    float Ac[16];
#pragma unroll
    for (int n = 0; n < 16; ++n) Ac[n] = -__expf(A_log[d * DSTATE + n]);
    const float Dk = Dskip[d];

    float h[16];
    size_t ho = (((size_t)b * NC + c) * DMODEL + d) * DSTATE;
#pragma unroll
    for (int n = 0; n < 16; ++n) h[n] = H0[ho + n];
    __syncthreads();

    const size_t base = ((size_t)b * L_SZ + (size_t)c * TCH) * DMODEL + d;
#pragma unroll 2
    for (int t = 0; t < TCH; ++t) {
        float dtv = bf2f(dt[base + (size_t)t * DMODEL]);
        float uv  = bf2f(u [base + (size_t)t * DMODEL]);
        float du = dtv * uv;
        float yv = 0.f;
#pragma unroll
        for (int n = 0; n < 16; ++n) {
            float a = __expf(dtv * Ac[n]);
            h[n] = fmaf(a, h[n], du * Bs[t][n]);
            yv = fmaf(h[n], Cs[t][n], yv);
        }
        yv = fmaf(uv, Dk, yv);
        yb[base + (size_t)t * DMODEL] = f2bf(yv);
        if (c == NC - 1 && t == TCH - 1) ylast[(size_t)b * DMODEL + d] = yv;
    }
}

// ---------------------------------------------------------------------------
// LayerNorm(last token) + head. One block per batch.
// ---------------------------------------------------------------------------
__global__ __launch_bounds__(256) void ln_head_kernel(
    const float* __restrict__ ylast, const float* __restrict__ g,
    const float* __restrict__ bb, const float* __restrict__ hw,
    const float* __restrict__ hb, float* __restrict__ out)
{
    const int b = blockIdx.x;
    const int tid = threadIdx.x;
    const float* row = ylast + (size_t)b * DMODEL;
    float v0 = row[tid], v1 = row[tid + 256];
    float s = v0 + v1;
    float s2 = v0 * v0 + v1 * v1;
#pragma unroll
    for (int o = 32; o >= 1; o >>= 1) {
        s += __shfl_xor(s, o);
        s2 += __shfl_xor(s2, o);
    }
    __shared__ float red[8];
    const int w = tid >> 6;
    if ((tid & 63) == 0) { red[w] = s; red[4 + w] = s2; }
    __syncthreads();
    s = red[0] + red[1] + red[2] + red[3];
    s2 = red[4] + red[5] + red[6] + red[7];
    float mu = s * (1.f / DMODEL);
    float var = s2 * (1.f / DMODEL) - mu * mu;
    float r = rsqrtf(var + LN_EPS);
    float c = ((v0 - mu) * r * g[tid] + bb[tid]) * hw[tid]
            + ((v1 - mu) * r * g[tid + 256] + bb[tid + 256]) * hw[tid + 256];
#pragma unroll
    for (int o = 32; o >= 1; o >>= 1) c += __shfl_xor(c, o);
    __syncthreads();
    if ((tid & 63) == 0) red[w] = c;
    __syncthreads();
    if (tid == 0) out[b] = red[0] + red[1] + red[2] + red[3] + hb[0];
}

// ---------------------------------------------------------------------------
extern "C" void kernel_launch(void* const* d_in, const int* in_sizes, int n_in,
                              void* d_out, int out_size, void* d_ws, size_t ws_size,
                              hipStream_t stream)
{
    const float* x      = (const float*)d_in[0];
    const float* W_in0  = (const float*)d_in[1];
    const float* b_in0  = (const float*)d_in[2];
    const float* W_in   = (const float*)d_in[3];
    const float* b_in   = (const float*)d_in[4];
    const float* A_log  = (const float*)d_in[5];
    const float* D_skip = (const float*)d_in[6];
    const float* W_dt   = (const float*)d_in[7];
    const float* b_dt   = (const float*)d_in[8];
    const float* W_B    = (const float*)d_in[9];
    const float* W_C    = (const float*)d_in[10];
    const float* ln_g   = (const float*)d_in[11];
    const float* ln_b   = (const float*)d_in[12];
    const float* head_w = (const float*)d_in[13];
    const float* head_b = (const float*)d_in[14];
    float* out = (float*)d_out;

    const size_t BLD = (size_t)B_SZ * L_SZ * DMODEL;         // 16.78M
    const size_t BLN = (size_t)B_SZ * L_SZ * DSTATE;         // 0.52M
    const size_t BCD = (size_t)B_SZ * NC * DMODEL * DSTATE;  // 2.10M
    const size_t XBN = (size_t)B_SZ * L_SZ * DIN;            // 2.10M

    // fp32 region (~29.4 MB), then bf16 region (~108.6 MB); total ~138 MB
    float* fp = (float*)d_ws;
    float* Bbuf  = fp; fp += BLN;
    float* Cbuf  = fp; fp += BLN;
    float* Pbuf  = fp; fp += BCD;
    float* Sbuf  = fp; fp += BCD;
    float* H0buf = fp; fp += BCD;
    float* ylast = fp; fp += (size_t)B_SZ * DMODEL;
    u16* hp = (u16*)fp;
    u16* xb   = hp; hp += XBN;
    u16* ub   = hp; hp += BLD;   // u bf16
    u16* dtb  = hp; hp += BLD;   // dt bf16
    u16* ybuf = hp; hp += BLD;   // layer output bf16 (next layer input)
    u16* WT0  = hp; hp += (size_t)DIN * DMODEL;
    u16* WTin = hp; hp += (size_t)(NLAYERS - 1) * DMODEL * DMODEL;
    u16* WTdt = hp; hp += (size_t)NLAYERS * DMODEL * DMODEL;

    const int M = B_SZ * L_SZ;   // 32768

    castx<<<(XBN / 4 + 255) / 256, 256, 0, stream>>>(x, xb, XBN / 4);
    wtrans<<<dim3(DIN / 32, DMODEL / 32, 1), 256, 0, stream>>>(W_in0, WT0, DIN, DMODEL);
    wtrans<<<dim3(DMODEL / 32, DMODEL / 32, NLAYERS - 1), 256, 0, stream>>>(W_in, WTin, DMODEL, DMODEL);
    wtrans<<<dim3(DMODEL / 32, DMODEL / 32, NLAYERS), 256, 0, stream>>>(W_dt, WTdt, DMODEL, DMODEL);

    for (int l = 0; l < NLAYERS; ++l) {
        const float* bu = (l == 0) ? b_in0 : b_in + (size_t)(l - 1) * DMODEL;

        if (l == 0) {
            gemm_mfma<0, 2, DIN><<<dim3(M / 128, DMODEL / 128), 256, 0, stream>>>(
                xb, WT0, bu, (float*)nullptr, ub, M, DMODEL);
        } else {
            gemm_mfma<0, 2, DMODEL><<<dim3(M / 128, DMODEL / 128), 256, 0, stream>>>(
                ybuf, WTin + (size_t)(l - 1) * DMODEL * DMODEL, bu,
                (float*)nullptr, ub, M, DMODEL);
        }
        gemm_mfma<1, 2, DMODEL><<<dim3(M / 128, DMODEL / 128), 256, 0, stream>>>(
            ub, WTdt + (size_t)l * DMODEL * DMODEL, b_dt + (size_t)l * DMODEL,
            (float*)nullptr, dtb, M, DMODEL);
        gemm_bc<<<M / 16, 256, 0, stream>>>(
            ub, W_B + (size_t)l * DMODEL * DSTATE,
            W_C + (size_t)l * DMODEL * DSTATE, Bbuf, Cbuf);
        const float* Al = A_log + (size_t)l * DMODEL * DSTATE;
        scan_pass1<<<dim3(DMODEL / 256, NC, B_SZ), 256, 0, stream>>>(
            ub, dtb, Bbuf, Al, Pbuf, Sbuf);
        scan_fix<<<(B_SZ * DMODEL * DSTATE) / 256, 256, 0, stream>>>(
            Pbuf, Sbuf, H0buf);
        scan_pass2<<<dim3(DMODEL / 256, NC, B_SZ), 256, 0, stream>>>(
            ub, dtb, Bbuf, Cbuf, Al, D_skip + (size_t)l * DMODEL,
            H0buf, ybuf, ylast);
    }

    ln_head_kernel<<<B_SZ, 256, 0, stream>>>(ylast, ln_g, ln_b, head_w, head_b, out);
}

// Round 6
// 911.407 us; speedup vs baseline: 5.8281x; 1.2625x over previous
//
#include <hip/hip_runtime.h>
#include <hip/hip_bf16.h>
#include <cstdint>
#include <cstddef>

#define B_SZ    16
#define L_SZ    2048
#define DIN     64
#define DMODEL  512
#define DSTATE  16
#define NLAYERS 4
#define LN_EPS  1e-5f
#define NC      16
#define TCH     (L_SZ / NC)   // 128

typedef __bf16 bf16x8 __attribute__((ext_vector_type(8)));
typedef float  f32x4  __attribute__((ext_vector_type(4)));
typedef unsigned short u16;
typedef unsigned int   u32;

__device__ __forceinline__ u16 f2bf(float f) {
    u32 u = __builtin_bit_cast(u32, f);
    u += 0x7fffu + ((u >> 16) & 1u);
    return (u16)(u >> 16);
}
__device__ __forceinline__ float bf2f(u16 v) {
    u32 u = ((u32)v) << 16;
    return __builtin_bit_cast(float, u);
}

__device__ __forceinline__ void gload16(const void* g, void* l) {
    __builtin_amdgcn_global_load_lds(
        (__attribute__((address_space(1))) void*)(g),
        (__attribute__((address_space(3))) void*)(l), 16, 0, 0);
}

// ---------------------------------------------------------------------------
// bf16 MFMA GEMM, double-buffered counted-vmcnt pipeline (T3-lite).
// A[M,K](bf16) @ BT[N,K]^T(bf16) + bias. 128x128 tile, BK=64, 4 waves.
// ACT=1: softplus. OUT: 2=bf16 only.
// ---------------------------------------------------------------------------
template <int ACT, int OUT, int K>
__global__ __launch_bounds__(256) void gemm_mfma(
    const u16* __restrict__ A, const u16* __restrict__ BT,
    const float* __restrict__ bias, float* __restrict__ C,
    u16* __restrict__ Cb, int M, int N)
{
    constexpr int BM = 128, BK = 64;
    constexpr int NT = K / BK;
    __shared__ u16 As[2][BM * BK];   // 2 x 16 KB
    __shared__ u16 Bs[2][BM * BK];   // 2 x 16 KB  (total 64 KB)

    const int tid = threadIdx.x;
    const int wv = tid >> 6, ln = tid & 63;
    const int bm = blockIdx.x * BM, bn = blockIdx.y * BM;
    const int wm = (wv >> 1) * 64, wn = (wv & 1) * 64;

    f32x4 acc[4][4];
#pragma unroll
    for (int i = 0; i < 4; ++i)
#pragma unroll
        for (int j = 0; j < 4; ++j) acc[i][j] = (f32x4){0.f, 0.f, 0.f, 0.f};

    auto stage = [&](int buf, int k0) {
#pragma unroll
        for (int i = 0; i < 4; ++i) {
            int t = i * 256 + tid;
            int m = t >> 3, s = t & 7;
            int ksrc = (s ^ (m & 7)) * 8;           // pre-swizzled source chunk
            gload16(A + (size_t)(bm + m) * K + k0 + ksrc,
                    &As[buf][(i * 256 + wv * 64) * 8]);
            gload16(BT + (size_t)(bn + m) * K + k0 + ksrc,
                    &Bs[buf][(i * 256 + wv * 64) * 8]);
        }
    };

    stage(0, 0);
    if (NT > 1) stage(1, BK);

#pragma unroll
    for (int kt = 0; kt < NT; ++kt) {
        if (kt == NT - 1) asm volatile("s_waitcnt vmcnt(0)" ::: "memory");
        else              asm volatile("s_waitcnt vmcnt(8)" ::: "memory");
        __builtin_amdgcn_s_barrier();

        const int buf = kt & 1;
#pragma unroll
        for (int ks = 0; ks < 2; ++ks) {
            bf16x8 af[4], bfr[4];
            const int g = ln >> 4, lm = ln & 15;
            const int c = ks * 4 + g;
#pragma unroll
            for (int f = 0; f < 4; ++f) {
                int ml = wm + f * 16 + lm;
                af[f] = *(const bf16x8*)&As[buf][ml * 64 + ((c ^ (ml & 7)) * 8)];
                int nl = wn + f * 16 + lm;
                bfr[f] = *(const bf16x8*)&Bs[buf][nl * 64 + ((c ^ (nl & 7)) * 8)];
            }
#pragma unroll
            for (int fm = 0; fm < 4; ++fm)
#pragma unroll
                for (int fn = 0; fn < 4; ++fn)
                    acc[fm][fn] = __builtin_amdgcn_mfma_f32_16x16x32_bf16(
                        af[fm], bfr[fn], acc[fm][fn], 0, 0, 0);
        }

        asm volatile("s_waitcnt lgkmcnt(0)" ::: "memory");
        __builtin_amdgcn_s_barrier();
        if (kt + 2 < NT) stage(buf, (kt + 2) * BK);
    }

    // C/D layout: col=lane&15, row=(lane>>4)*4+reg  [verified m89/m91]
    const int cg = ln >> 4, lc = ln & 15;
#pragma unroll
    for (int fm = 0; fm < 4; ++fm) {
#pragma unroll
        for (int fn = 0; fn < 4; ++fn) {
            int col = bn + wn + fn * 16 + lc;
            float bv = bias[col];
#pragma unroll
            for (int r = 0; r < 4; ++r) {
                int row = bm + wm + fm * 16 + cg * 4 + r;
                float v = acc[fm][fn][r] + bv;
                if (ACT == 1) v = (v > 20.f) ? v : __logf(1.f + __expf(v));
                size_t o = (size_t)row * N + col;
                if (OUT != 2) C[o] = v;
                if (OUT >= 1) Cb[o] = f2bf(v);
            }
        }
    }
}

// ---------------------------------------------------------------------------
// Weight transpose + cast: WT[N][K] (bf16) from W[K][N] (f32). 32x32 tiles.
// ---------------------------------------------------------------------------
__global__ __launch_bounds__(256) void wtrans(
    const float* __restrict__ W, u16* __restrict__ WT, int K, int N)
{
    __shared__ float tile[32][33];
    const float* Wm = W + (size_t)blockIdx.z * K * N;
    u16* WTm = WT + (size_t)blockIdx.z * K * N;
    int k0 = blockIdx.x * 32, n0 = blockIdx.y * 32;
    int tx = threadIdx.x & 31, ty = threadIdx.x >> 5;
#pragma unroll
    for (int i = 0; i < 4; ++i)
        tile[ty + 8 * i][tx] = Wm[(size_t)(k0 + ty + 8 * i) * N + n0 + tx];
    __syncthreads();
#pragma unroll
    for (int i = 0; i < 4; ++i)
        WTm[(size_t)(n0 + ty + 8 * i) * K + k0 + tx] = f2bf(tile[tx][ty + 8 * i]);
}

// x -> bf16 cast
__global__ __launch_bounds__(256) void castx(
    const float* __restrict__ x, u16* __restrict__ xb, int n4)
{
    int i = blockIdx.x * 256 + threadIdx.x;
    if (i < n4) {
        float4 v = ((const float4*)x)[i];
        ushort4 o;
        o.x = f2bf(v.x); o.y = f2bf(v.y); o.z = f2bf(v.z); o.w = f2bf(v.w);
        ((ushort4*)xb)[i] = o;
    }
}

// ---------------------------------------------------------------------------
// Pack W_B,W_C ([L][512][16] f32) -> WBCT [L][32][512] bf16 (transposed).
// Rows 0-15 = W_B^T, rows 16-31 = W_C^T. One elem per thread.
// ---------------------------------------------------------------------------
__global__ __launch_bounds__(256) void prep_wbc(
    const float* __restrict__ WB, const float* __restrict__ WC,
    u16* __restrict__ WBCT)
{
    int idx = blockIdx.x * 256 + threadIdx.x;      // over NLAYERS*32*512
    int l = idx >> 14;                             // 32*512 = 16384
    int r = idx & 16383;
    int n = r >> 9, k = r & 511;
    float v = (n < 16) ? WB[((size_t)l * DMODEL + k) * DSTATE + n]
                       : WC[((size_t)l * DMODEL + k) * DSTATE + (n - 16)];
    WBCT[((size_t)l * 32 + n) * DMODEL + k] = f2bf(v);
}

// ---------------------------------------------------------------------------
// MFMA B/C projection: Bo/Co[M,16](f32) = u[M,512](bf16) @ {W_B,W_C}.
// Wave computes one 16-row x (16 B + 16 C) strip straight from global
// (u and WBCT are L2/L3 resident). Grid = M/64, 4 waves/block.
// ---------------------------------------------------------------------------
__global__ __launch_bounds__(256) void gemm_bc_mfma(
    const u16* __restrict__ A, const u16* __restrict__ WBCT,
    float* __restrict__ Bo, float* __restrict__ Co)
{
    const int tid = threadIdx.x;
    const int wv = tid >> 6, ln = tid & 63;
    const int m0 = blockIdx.x * 64 + wv * 16;
    const int g = ln >> 4, lm = ln & 15;

    f32x4 accB = (f32x4){0.f, 0.f, 0.f, 0.f};
    f32x4 accC = (f32x4){0.f, 0.f, 0.f, 0.f};
    const u16* arow = A + (size_t)(m0 + lm) * DMODEL;
    const u16* wb = WBCT + (size_t)lm * DMODEL;
    const u16* wc = WBCT + (size_t)(lm + 16) * DMODEL;
#pragma unroll
    for (int ks = 0; ks < DMODEL / 32; ++ks) {
        int ko = ks * 32 + g * 8;
        bf16x8 a = *(const bf16x8*)&arow[ko];
        bf16x8 b = *(const bf16x8*)&wb[ko];
        bf16x8 c = *(const bf16x8*)&wc[ko];
        accB = __builtin_amdgcn_mfma_f32_16x16x32_bf16(a, b, accB, 0, 0, 0);
        accC = __builtin_amdgcn_mfma_f32_16x16x32_bf16(a, c, accC, 0, 0, 0);
    }
    // D layout: col = lane&15 (n), row = g*4+r
#pragma unroll
    for (int r = 0; r < 4; ++r) {
        int m = m0 + g * 4 + r;
        Bo[(size_t)m * DSTATE + lm] = accB[r];
        Co[(size_t)m * DSTATE + lm] = accC[r];
    }
}

// ---------------------------------------------------------------------------
// Scan pass 1: thread = one d, h[n] in regs. B-chunk staged in LDS.
// ---------------------------------------------------------------------------
__global__ __launch_bounds__(256) void scan_pass1(
    const u16* __restrict__ u, const u16* __restrict__ dt,
    const float* __restrict__ Bm, const float* __restrict__ A_log,
    float* __restrict__ P, float* __restrict__ S)
{
    const int tid = threadIdx.x;
    const int d = blockIdx.x * 256 + tid;
    const int c = blockIdx.y, b = blockIdx.z;
    __shared__ float Bs[TCH][DSTATE];

    const float* Bsrc = Bm + ((size_t)b * L_SZ + (size_t)c * TCH) * DSTATE;
    for (int i = tid; i < TCH * DSTATE / 4; i += 256)
        ((float4*)Bs)[i] = ((const float4*)Bsrc)[i];

    float Ac[16];
#pragma unroll
    for (int n = 0; n < 16; ++n) Ac[n] = -__expf(A_log[d * DSTATE + n]);
    __syncthreads();

    float p[16], s[16];
#pragma unroll
    for (int n = 0; n < 16; ++n) { p[n] = 1.f; s[n] = 0.f; }

    const size_t base = ((size_t)b * L_SZ + (size_t)c * TCH) * DMODEL + d;
#pragma unroll 2
    for (int t = 0; t < TCH; ++t) {
        float dtv = bf2f(dt[base + (size_t)t * DMODEL]);
        float uv  = bf2f(u [base + (size_t)t * DMODEL]);
        float du = dtv * uv;
#pragma unroll
        for (int n = 0; n < 16; ++n) {
            float a = __expf(dtv * Ac[n]);
            p[n] *= a;
            s[n] = fmaf(a, s[n], du * Bs[t][n]);
        }
    }
    size_t o = (((size_t)b * NC + c) * DMODEL + d) * DSTATE;
#pragma unroll
    for (int n = 0; n < 16; ++n) { P[o + n] = p[n]; S[o + n] = s[n]; }
}

// ---------------------------------------------------------------------------
// Chunk fix-up: sequential over NC chunks per (b,d,n).
// ---------------------------------------------------------------------------
__global__ __launch_bounds__(256) void scan_fix(
    const float* __restrict__ P, const float* __restrict__ S,
    float* __restrict__ H0)
{
    const int idx = blockIdx.x * 256 + threadIdx.x;   // over B*D*N
    const int dn = idx & (DMODEL * DSTATE - 1);
    const int b = idx >> 13;                          // D*N = 8192
    float h = 0.f;
#pragma unroll
    for (int c = 0; c < NC; ++c) {
        size_t o = (((size_t)b * NC + c) << 13) + dn;
        H0[o] = h;
        h = fmaf(P[o], h, S[o]);
    }
}

// ---------------------------------------------------------------------------
// Scan pass 2: seeded with H0; emit y as bf16 (+ fp32 last-token row).
// ---------------------------------------------------------------------------
__global__ __launch_bounds__(256) void scan_pass2(
    const u16* __restrict__ u, const u16* __restrict__ dt,
    const float* __restrict__ Bm, const float* __restrict__ Cm,
    const float* __restrict__ A_log, const float* __restrict__ Dskip,
    const float* __restrict__ H0, u16* __restrict__ yb,
    float* __restrict__ ylast)
{
    const int tid = threadIdx.x;
    const int d = blockIdx.x * 256 + tid;
    const int c = blockIdx.y, b = blockIdx.z;
    __shared__ float Bs[TCH][DSTATE];
    __shared__ float Cs[TCH][DSTATE];

    const float* Bsrc = Bm + ((size_t)b * L_SZ + (size_t)c * TCH) * DSTATE;
    const float* Csrc = Cm + ((size_t)b * L_SZ + (size_t)c * TCH) * DSTATE;
    for (int i = tid; i < TCH * DSTATE / 4; i += 256) {
        ((float4*)Bs)[i] = ((const float4*)Bsrc)[i];
        ((float4*)Cs)[i] = ((const float4*)Csrc)[i];
    }

    float Ac[16];
#pragma unroll
    for (int n = 0; n < 16; ++n) Ac[n] = -__expf(A_log[d * DSTATE + n]);
    const float Dk = Dskip[d];

    float h[16];
    size_t ho = (((size_t)b * NC + c) * DMODEL + d) * DSTATE;
#pragma unroll
    for (int n = 0; n < 16; ++n) h[n] = H0[ho + n];
    __syncthreads();

    const size_t base = ((size_t)b * L_SZ + (size_t)c * TCH) * DMODEL + d;
#pragma unroll 2
    for (int t = 0; t < TCH; ++t) {
        float dtv = bf2f(dt[base + (size_t)t * DMODEL]);
        float uv  = bf2f(u [base + (size_t)t * DMODEL]);
        float du = dtv * uv;
        float yv = 0.f;
#pragma unroll
        for (int n = 0; n < 16; ++n) {
            float a = __expf(dtv * Ac[n]);
            h[n] = fmaf(a, h[n], du * Bs[t][n]);
            yv = fmaf(h[n], Cs[t][n], yv);
        }
        yv = fmaf(uv, Dk, yv);
        yb[base + (size_t)t * DMODEL] = f2bf(yv);
        if (c == NC - 1 && t == TCH - 1) ylast[(size_t)b * DMODEL + d] = yv;
    }
}

// ---------------------------------------------------------------------------
// LayerNorm(last token) + head. One block per batch.
// ---------------------------------------------------------------------------
__global__ __launch_bounds__(256) void ln_head_kernel(
    const float* __restrict__ ylast, const float* __restrict__ g,
    const float* __restrict__ bb, const float* __restrict__ hw,
    const float* __restrict__ hb, float* __restrict__ out)
{
    const int b = blockIdx.x;
    const int tid = threadIdx.x;
    const float* row = ylast + (size_t)b * DMODEL;
    float v0 = row[tid], v1 = row[tid + 256];
    float s = v0 + v1;
    float s2 = v0 * v0 + v1 * v1;
#pragma unroll
    for (int o = 32; o >= 1; o >>= 1) {
        s += __shfl_xor(s, o);
        s2 += __shfl_xor(s2, o);
    }
    __shared__ float red[8];
    const int w = tid >> 6;
    if ((tid & 63) == 0) { red[w] = s; red[4 + w] = s2; }
    __syncthreads();
    s = red[0] + red[1] + red[2] + red[3];
    s2 = red[4] + red[5] + red[6] + red[7];
    float mu = s * (1.f / DMODEL);
    float var = s2 * (1.f / DMODEL) - mu * mu;
    float r = rsqrtf(var + LN_EPS);
    float c = ((v0 - mu) * r * g[tid] + bb[tid]) * hw[tid]
            + ((v1 - mu) * r * g[tid + 256] + bb[tid + 256]) * hw[tid + 256];
#pragma unroll
    for (int o = 32; o >= 1; o >>= 1) c += __shfl_xor(c, o);
    __syncthreads();
    if ((tid & 63) == 0) red[w] = c;
    __syncthreads();
    if (tid == 0) out[b] = red[0] + red[1] + red[2] + red[3] + hb[0];
}

// ---------------------------------------------------------------------------
extern "C" void kernel_launch(void* const* d_in, const int* in_sizes, int n_in,
                              void* d_out, int out_size, void* d_ws, size_t ws_size,
                              hipStream_t stream)
{
    const float* x      = (const float*)d_in[0];
    const float* W_in0  = (const float*)d_in[1];
    const float* b_in0  = (const float*)d_in[2];
    const float* W_in   = (const float*)d_in[3];
    const float* b_in   = (const float*)d_in[4];
    const float* A_log  = (const float*)d_in[5];
    const float* D_skip = (const float*)d_in[6];
    const float* W_dt   = (const float*)d_in[7];
    const float* b_dt   = (const float*)d_in[8];
    const float* W_B    = (const float*)d_in[9];
    const float* W_C    = (const float*)d_in[10];
    const float* ln_g   = (const float*)d_in[11];
    const float* ln_b   = (const float*)d_in[12];
    const float* head_w = (const float*)d_in[13];
    const float* head_b = (const float*)d_in[14];
    float* out = (float*)d_out;

    const size_t BLD = (size_t)B_SZ * L_SZ * DMODEL;         // 16.78M
    const size_t BLN = (size_t)B_SZ * L_SZ * DSTATE;         // 0.52M
    const size_t BCD = (size_t)B_SZ * NC * DMODEL * DSTATE;  // 2.10M
    const size_t XBN = (size_t)B_SZ * L_SZ * DIN;            // 2.10M

    // fp32 region (~29.4 MB), then bf16 region (~108.8 MB); total ~138 MB
    float* fp = (float*)d_ws;
    float* Bbuf  = fp; fp += BLN;
    float* Cbuf  = fp; fp += BLN;
    float* Pbuf  = fp; fp += BCD;
    float* Sbuf  = fp; fp += BCD;
    float* H0buf = fp; fp += BCD;
    float* ylast = fp; fp += (size_t)B_SZ * DMODEL;
    u16* hp = (u16*)fp;
    u16* xb   = hp; hp += XBN;
    u16* ub   = hp; hp += BLD;   // u bf16
    u16* dtb  = hp; hp += BLD;   // dt bf16
    u16* ybuf = hp; hp += BLD;   // layer output bf16 (next layer input)
    u16* WT0  = hp; hp += (size_t)DIN * DMODEL;
    u16* WTin = hp; hp += (size_t)(NLAYERS - 1) * DMODEL * DMODEL;
    u16* WTdt = hp; hp += (size_t)NLAYERS * DMODEL * DMODEL;
    u16* WBCT = hp; hp += (size_t)NLAYERS * 32 * DMODEL;

    const int M = B_SZ * L_SZ;   // 32768

    castx<<<(XBN / 4 + 255) / 256, 256, 0, stream>>>(x, xb, XBN / 4);
    wtrans<<<dim3(DIN / 32, DMODEL / 32, 1), 256, 0, stream>>>(W_in0, WT0, DIN, DMODEL);
    wtrans<<<dim3(DMODEL / 32, DMODEL / 32, NLAYERS - 1), 256, 0, stream>>>(W_in, WTin, DMODEL, DMODEL);
    wtrans<<<dim3(DMODEL / 32, DMODEL / 32, NLAYERS), 256, 0, stream>>>(W_dt, WTdt, DMODEL, DMODEL);
    prep_wbc<<<(NLAYERS * 32 * DMODEL) / 256, 256, 0, stream>>>(W_B, W_C, WBCT);

    for (int l = 0; l < NLAYERS; ++l) {
        const float* bu = (l == 0) ? b_in0 : b_in + (size_t)(l - 1) * DMODEL;

        if (l == 0) {
            gemm_mfma<0, 2, DIN><<<dim3(M / 128, DMODEL / 128), 256, 0, stream>>>(
                xb, WT0, bu, (float*)nullptr, ub, M, DMODEL);
        } else {
            gemm_mfma<0, 2, DMODEL><<<dim3(M / 128, DMODEL / 128), 256, 0, stream>>>(
                ybuf, WTin + (size_t)(l - 1) * DMODEL * DMODEL, bu,
                (float*)nullptr, ub, M, DMODEL);
        }
        gemm_mfma<1, 2, DMODEL><<<dim3(M / 128, DMODEL / 128), 256, 0, stream>>>(
            ub, WTdt + (size_t)l * DMODEL * DMODEL, b_dt + (size_t)l * DMODEL,
            (float*)nullptr, dtb, M, DMODEL);
        gemm_bc_mfma<<<M / 64, 256, 0, stream>>>(
            ub, WBCT + (size_t)l * 32 * DMODEL, Bbuf, Cbuf);
        const float* Al = A_log + (size_t)l * DMODEL * DSTATE;
        scan_pass1<<<dim3(DMODEL / 256, NC, B_SZ), 256, 0, stream>>>(
            ub, dtb, Bbuf, Al, Pbuf, Sbuf);
        scan_fix<<<(B_SZ * DMODEL * DSTATE) / 256, 256, 0, stream>>>(
            Pbuf, Sbuf, H0buf);
        scan_pass2<<<dim3(DMODEL / 256, NC, B_SZ), 256, 0, stream>>>(
            ub, dtb, Bbuf, Cbuf, Al, D_skip + (size_t)l * DMODEL,
            H0buf, ybuf, ylast);
    }

    ln_head_kernel<<<B_SZ, 256, 0, stream>>>(ylast, ln_g, ln_b, head_w, head_b, out);
}

// Round 7
// 901.453 us; speedup vs baseline: 5.8925x; 1.0110x over previous
//
#include <hip/hip_runtime.h>
#include <hip/hip_bf16.h>
#include <cstdint>
#include <cstddef>

#define B_SZ    16
#define L_SZ    2048
#define DIN     64
#define DMODEL  512
#define DSTATE  16
#define NLAYERS 4
#define LN_EPS  1e-5f
#define NC      32
#define TCH     (L_SZ / NC)   // 64

typedef __bf16 bf16x8 __attribute__((ext_vector_type(8)));
typedef float  f32x4  __attribute__((ext_vector_type(4)));
typedef unsigned short u16;
typedef unsigned int   u32;

__device__ __forceinline__ u16 f2bf(float f) {
    u32 u = __builtin_bit_cast(u32, f);
    u += 0x7fffu + ((u >> 16) & 1u);
    return (u16)(u >> 16);
}
__device__ __forceinline__ float bf2f(u16 v) {
    u32 u = ((u32)v) << 16;
    return __builtin_bit_cast(float, u);
}

// a_[n] = q^(n+1), n in [0,16): ~15 muls, shallow tree
__device__ __forceinline__ void pow16(float q, float* a_) {
    float q2 = q * q, q4 = q2 * q2, q8 = q4 * q4;
    a_[0] = q;        a_[1] = q2;       a_[2] = q2 * q;   a_[3] = q4;
    a_[4] = q4 * q;   a_[5] = q4 * q2;  a_[6] = a_[5] * q; a_[7] = q8;
    a_[8] = q8 * q;   a_[9] = q8 * q2;  a_[10] = a_[9] * q; a_[11] = q8 * q4;
    a_[12] = a_[11] * q; a_[13] = a_[11] * q2; a_[14] = a_[13] * q; a_[15] = q8 * q8;
}

#define LOG2E 1.4426950408889634f

// ---------------------------------------------------------------------------
// Register-direct bf16 MFMA GEMM (no LDS, no barriers).
// C[M,N] = A[M,K] @ BT[N,K]^T + bias. 128x128 block, 4 waves (2x2),
// wave tile 64x64 = 4x4 frags of 16x16x32. Operand frags loaded straight
// global->VGPR (weights + streamed A are L2/L3 resident), 2-buffer register
// pingpong: step k+1's 8 loads issue before step k's 16 MFMAs.
// ACT=1: softplus. OUT: 2 = bf16 only.
// ---------------------------------------------------------------------------
template <int ACT, int OUT, int K>
__global__ __launch_bounds__(256) void gemm_mfma(
    const u16* __restrict__ A, const u16* __restrict__ BT,
    const float* __restrict__ bias, float* __restrict__ C,
    u16* __restrict__ Cb, int M, int N)
{
    constexpr int NT = K / 32;
    const int tid = threadIdx.x;
    const int wv = tid >> 6, ln = tid & 63;
    const int bm = blockIdx.x * 128, bn = blockIdx.y * 128;
    const int wm = (wv >> 1) * 64, wn = (wv & 1) * 64;
    const int g = ln >> 4, lm = ln & 15;

    const u16* ap[4];
    const u16* bp[4];
#pragma unroll
    for (int f = 0; f < 4; ++f) {
        ap[f] = A  + (size_t)(bm + wm + f * 16 + lm) * K + g * 8;
        bp[f] = BT + (size_t)(bn + wn + f * 16 + lm) * K + g * 8;
    }

    f32x4 acc[4][4];
#pragma unroll
    for (int i = 0; i < 4; ++i)
#pragma unroll
        for (int j = 0; j < 4; ++j) acc[i][j] = (f32x4){0.f, 0.f, 0.f, 0.f};

    bf16x8 a0[4], b0[4], a1[4], b1[4];
#pragma unroll
    for (int f = 0; f < 4; ++f) {
        a0[f] = *(const bf16x8*)(ap[f]);
        b0[f] = *(const bf16x8*)(bp[f]);
    }

    // one pipeline step: prefetch (kt+1) into (na,nb), MFMA on (ca,cb)
    auto step = [&](bf16x8 (&ca)[4], bf16x8 (&cb)[4],
                    bf16x8 (&na)[4], bf16x8 (&nb)[4], int kt) {
        if (kt + 1 < NT) {
#pragma unroll
            for (int f = 0; f < 4; ++f) {
                na[f] = *(const bf16x8*)(ap[f] + (kt + 1) * 32);
                nb[f] = *(const bf16x8*)(bp[f] + (kt + 1) * 32);
            }
        }
#pragma unroll
        for (int fm = 0; fm < 4; ++fm)
#pragma unroll
            for (int fn = 0; fn < 4; ++fn)
                acc[fm][fn] = __builtin_amdgcn_mfma_f32_16x16x32_bf16(
                    ca[fm], cb[fn], acc[fm][fn], 0, 0, 0);
    };

#pragma unroll
    for (int kt = 0; kt < NT; kt += 2) {
        step(a0, b0, a1, b1, kt);
        if (kt + 1 < NT) step(a1, b1, a0, b0, kt + 1);
    }

    // C/D layout: col=lane&15, row=(lane>>4)*4+reg  [verified m89/m91]
#pragma unroll
    for (int fm = 0; fm < 4; ++fm) {
#pragma unroll
        for (int fn = 0; fn < 4; ++fn) {
            int col = bn + wn + fn * 16 + lm;
            float bv = bias[col];
#pragma unroll
            for (int r = 0; r < 4; ++r) {
                int row = bm + wm + fm * 16 + g * 4 + r;
                float v = acc[fm][fn][r] + bv;
                if (ACT == 1) v = (v > 20.f) ? v : __logf(1.f + __expf(v));
                size_t o = (size_t)row * N + col;
                if (OUT != 2) C[o] = v;
                if (OUT >= 1) Cb[o] = f2bf(v);
            }
        }
    }
}

// ---------------------------------------------------------------------------
// Weight transpose + cast: WT[N][K] (bf16) from W[K][N] (f32). 32x32 tiles.
// ---------------------------------------------------------------------------
__global__ __launch_bounds__(256) void wtrans(
    const float* __restrict__ W, u16* __restrict__ WT, int K, int N)
{
    __shared__ float tile[32][33];
    const float* Wm = W + (size_t)blockIdx.z * K * N;
    u16* WTm = WT + (size_t)blockIdx.z * K * N;
    int k0 = blockIdx.x * 32, n0 = blockIdx.y * 32;
    int tx = threadIdx.x & 31, ty = threadIdx.x >> 5;
#pragma unroll
    for (int i = 0; i < 4; ++i)
        tile[ty + 8 * i][tx] = Wm[(size_t)(k0 + ty + 8 * i) * N + n0 + tx];
    __syncthreads();
#pragma unroll
    for (int i = 0; i < 4; ++i)
        WTm[(size_t)(n0 + ty + 8 * i) * K + k0 + tx] = f2bf(tile[tx][ty + 8 * i]);
}

// x -> bf16 cast
__global__ __launch_bounds__(256) void castx(
    const float* __restrict__ x, u16* __restrict__ xb, int n4)
{
    int i = blockIdx.x * 256 + threadIdx.x;
    if (i < n4) {
        float4 v = ((const float4*)x)[i];
        ushort4 o;
        o.x = f2bf(v.x); o.y = f2bf(v.y); o.z = f2bf(v.z); o.w = f2bf(v.w);
        ((ushort4*)xb)[i] = o;
    }
}

// ---------------------------------------------------------------------------
// Pack W_B,W_C ([L][512][16] f32) -> WBCT [L][32][512] bf16 (transposed).
// ---------------------------------------------------------------------------
__global__ __launch_bounds__(256) void prep_wbc(
    const float* __restrict__ WB, const float* __restrict__ WC,
    u16* __restrict__ WBCT)
{
    int idx = blockIdx.x * 256 + threadIdx.x;      // over NLAYERS*32*512
    int l = idx >> 14;                             // 32*512 = 16384
    int r = idx & 16383;
    int n = r >> 9, k = r & 511;
    float v = (n < 16) ? WB[((size_t)l * DMODEL + k) * DSTATE + n]
                       : WC[((size_t)l * DMODEL + k) * DSTATE + (n - 16)];
    WBCT[((size_t)l * 32 + n) * DMODEL + k] = f2bf(v);
}

// ---------------------------------------------------------------------------
// MFMA B/C projection: Bo/Co[M,16](f32) = u[M,512](bf16) @ {W_B,W_C}.
// ---------------------------------------------------------------------------
__global__ __launch_bounds__(256) void gemm_bc_mfma(
    const u16* __restrict__ A, const u16* __restrict__ WBCT,
    float* __restrict__ Bo, float* __restrict__ Co)
{
    const int tid = threadIdx.x;
    const int wv = tid >> 6, ln = tid & 63;
    const int m0 = blockIdx.x * 64 + wv * 16;
    const int g = ln >> 4, lm = ln & 15;

    f32x4 accB = (f32x4){0.f, 0.f, 0.f, 0.f};
    f32x4 accC = (f32x4){0.f, 0.f, 0.f, 0.f};
    const u16* arow = A + (size_t)(m0 + lm) * DMODEL;
    const u16* wb = WBCT + (size_t)lm * DMODEL;
    const u16* wc = WBCT + (size_t)(lm + 16) * DMODEL;
#pragma unroll
    for (int ks = 0; ks < DMODEL / 32; ++ks) {
        int ko = ks * 32 + g * 8;
        bf16x8 a = *(const bf16x8*)&arow[ko];
        bf16x8 b = *(const bf16x8*)&wb[ko];
        bf16x8 c = *(const bf16x8*)&wc[ko];
        accB = __builtin_amdgcn_mfma_f32_16x16x32_bf16(a, b, accB, 0, 0, 0);
        accC = __builtin_amdgcn_mfma_f32_16x16x32_bf16(a, c, accC, 0, 0, 0);
    }
#pragma unroll
    for (int r = 0; r < 4; ++r) {
        int m = m0 + g * 4 + r;
        Bo[(size_t)m * DSTATE + lm] = accB[r];
        Co[(size_t)m * DSTATE + lm] = accC[r];
    }
}

// ---------------------------------------------------------------------------
// Scan pass 1: thread = one d, h[n] in regs. B-chunk staged in LDS.
// Fast path exploits A_log[d][n] = log(n+1): a[n] = q^(n+1), q = exp2(c*dt);
// chunk decay product tracked as a single running qprod. Guarded by a
// geometric-ratio check (wave-uniform); falls back to 16-exp loop.
// ---------------------------------------------------------------------------
__global__ __launch_bounds__(256) void scan_pass1(
    const u16* __restrict__ u, const u16* __restrict__ dt,
    const float* __restrict__ Bm, const float* __restrict__ A_log,
    float* __restrict__ P, float* __restrict__ S)
{
    const int tid = threadIdx.x;
    const int d = blockIdx.x * 256 + tid;
    const int c = blockIdx.y, b = blockIdx.z;
    __shared__ float Bs[TCH][DSTATE];

    const float* Bsrc = Bm + ((size_t)b * L_SZ + (size_t)c * TCH) * DSTATE;
    for (int i = tid; i < TCH * DSTATE / 4; i += 256)
        ((float4*)Bs)[i] = ((const float4*)Bsrc)[i];

    float Ac[16];
#pragma unroll
    for (int n = 0; n < 16; ++n) Ac[n] = -__expf(A_log[d * DSTATE + n]);
    bool geo = true;
#pragma unroll
    for (int n = 1; n < 16; ++n)
        geo &= fabsf(Ac[n] - (n + 1) * Ac[0]) <= 1e-4f * (n + 1) * fabsf(Ac[0]);
    __syncthreads();

    float s[16];
#pragma unroll
    for (int n = 0; n < 16; ++n) s[n] = 0.f;

    const size_t base = ((size_t)b * L_SZ + (size_t)c * TCH) * DMODEL + d;
    size_t o = (((size_t)b * NC + c) * DMODEL + d) * DSTATE;

    if (geo) {
        const float cK = Ac[0] * LOG2E;
        float qp = 1.f;
#pragma unroll 2
        for (int t = 0; t < TCH; ++t) {
            float dtv = bf2f(dt[base + (size_t)t * DMODEL]);
            float uv  = bf2f(u [base + (size_t)t * DMODEL]);
            float du = dtv * uv;
            float q = exp2f(dtv * cK);
            qp *= q;
            float a_[16];
            pow16(q, a_);
#pragma unroll
            for (int n = 0; n < 16; ++n)
                s[n] = fmaf(a_[n], s[n], du * Bs[t][n]);
        }
        float p_[16];
        pow16(qp, p_);
#pragma unroll
        for (int n = 0; n < 16; ++n) { P[o + n] = p_[n]; S[o + n] = s[n]; }
    } else {
        float p[16];
#pragma unroll
        for (int n = 0; n < 16; ++n) p[n] = 1.f;
#pragma unroll 2
        for (int t = 0; t < TCH; ++t) {
            float dtv = bf2f(dt[base + (size_t)t * DMODEL]);
            float uv  = bf2f(u [base + (size_t)t * DMODEL]);
            float du = dtv * uv;
#pragma unroll
            for (int n = 0; n < 16; ++n) {
                float a = __expf(dtv * Ac[n]);
                p[n] *= a;
                s[n] = fmaf(a, s[n], du * Bs[t][n]);
            }
        }
#pragma unroll
        for (int n = 0; n < 16; ++n) { P[o + n] = p[n]; S[o + n] = s[n]; }
    }
}

// ---------------------------------------------------------------------------
// Chunk fix-up: sequential over NC chunks per (b,d,n).
// ---------------------------------------------------------------------------
__global__ __launch_bounds__(256) void scan_fix(
    const float* __restrict__ P, const float* __restrict__ S,
    float* __restrict__ H0)
{
    const int idx = blockIdx.x * 256 + threadIdx.x;   // over B*D*N
    const int dn = idx & (DMODEL * DSTATE - 1);
    const int b = idx >> 13;                          // D*N = 8192
    float h = 0.f;
#pragma unroll
    for (int c = 0; c < NC; ++c) {
        size_t o = (((size_t)b * NC + c) << 13) + dn;
        H0[o] = h;
        h = fmaf(P[o], h, S[o]);
    }
}

// ---------------------------------------------------------------------------
// Scan pass 2: seeded with H0; emit y bf16 (+ fp32 last-token row).
// ---------------------------------------------------------------------------
__global__ __launch_bounds__(256) void scan_pass2(
    const u16* __restrict__ u, const u16* __restrict__ dt,
    const float* __restrict__ Bm, const float* __restrict__ Cm,
    const float* __restrict__ A_log, const float* __restrict__ Dskip,
    const float* __restrict__ H0, u16* __restrict__ yb,
    float* __restrict__ ylast)
{
    const int tid = threadIdx.x;
    const int d = blockIdx.x * 256 + tid;
    const int c = blockIdx.y, b = blockIdx.z;
    __shared__ float Bs[TCH][DSTATE];
    __shared__ float Cs[TCH][DSTATE];

    const float* Bsrc = Bm + ((size_t)b * L_SZ + (size_t)c * TCH) * DSTATE;
    const float* Csrc = Cm + ((size_t)b * L_SZ + (size_t)c * TCH) * DSTATE;
    for (int i = tid; i < TCH * DSTATE / 4; i += 256) {
        ((float4*)Bs)[i] = ((const float4*)Bsrc)[i];
        ((float4*)Cs)[i] = ((const float4*)Csrc)[i];
    }

    float Ac[16];
#pragma unroll
    for (int n = 0; n < 16; ++n) Ac[n] = -__expf(A_log[d * DSTATE + n]);
    bool geo = true;
#pragma unroll
    for (int n = 1; n < 16; ++n)
        geo &= fabsf(Ac[n] - (n + 1) * Ac[0]) <= 1e-4f * (n + 1) * fabsf(Ac[0]);
    const float Dk = Dskip[d];

    float h[16];
    size_t ho = (((size_t)b * NC + c) * DMODEL + d) * DSTATE;
#pragma unroll
    for (int n = 0; n < 16; ++n) h[n] = H0[ho + n];
    __syncthreads();

    const size_t base = ((size_t)b * L_SZ + (size_t)c * TCH) * DMODEL + d;

    if (geo) {
        const float cK = Ac[0] * LOG2E;
#pragma unroll 2
        for (int t = 0; t < TCH; ++t) {
            float dtv = bf2f(dt[base + (size_t)t * DMODEL]);
            float uv  = bf2f(u [base + (size_t)t * DMODEL]);
            float du = dtv * uv;
            float q = exp2f(dtv * cK);
            float a_[16];
            pow16(q, a_);
            float yv = 0.f;
#pragma unroll
            for (int n = 0; n < 16; ++n) {
                h[n] = fmaf(a_[n], h[n], du * Bs[t][n]);
                yv = fmaf(h[n], Cs[t][n], yv);
            }
            yv = fmaf(uv, Dk, yv);
            yb[base + (size_t)t * DMODEL] = f2bf(yv);
            if (c == NC - 1 && t == TCH - 1) ylast[(size_t)b * DMODEL + d] = yv;
        }
    } else {
#pragma unroll 2
        for (int t = 0; t < TCH; ++t) {
            float dtv = bf2f(dt[base + (size_t)t * DMODEL]);
            float uv  = bf2f(u [base + (size_t)t * DMODEL]);
            float du = dtv * uv;
            float yv = 0.f;
#pragma unroll
            for (int n = 0; n < 16; ++n) {
                float a = __expf(dtv * Ac[n]);
                h[n] = fmaf(a, h[n], du * Bs[t][n]);
                yv = fmaf(h[n], Cs[t][n], yv);
            }
            yv = fmaf(uv, Dk, yv);
            yb[base + (size_t)t * DMODEL] = f2bf(yv);
            if (c == NC - 1 && t == TCH - 1) ylast[(size_t)b * DMODEL + d] = yv;
        }
    }
}

// ---------------------------------------------------------------------------
// LayerNorm(last token) + head. One block per batch.
// ---------------------------------------------------------------------------
__global__ __launch_bounds__(256) void ln_head_kernel(
    const float* __restrict__ ylast, const float* __restrict__ g,
    const float* __restrict__ bb, const float* __restrict__ hw,
    const float* __restrict__ hb, float* __restrict__ out)
{
    const int b = blockIdx.x;
    const int tid = threadIdx.x;
    const float* row = ylast + (size_t)b * DMODEL;
    float v0 = row[tid], v1 = row[tid + 256];
    float s = v0 + v1;
    float s2 = v0 * v0 + v1 * v1;
#pragma unroll
    for (int o = 32; o >= 1; o >>= 1) {
        s += __shfl_xor(s, o);
        s2 += __shfl_xor(s2, o);
    }
    __shared__ float red[8];
    const int w = tid >> 6;
    if ((tid & 63) == 0) { red[w] = s; red[4 + w] = s2; }
    __syncthreads();
    s = red[0] + red[1] + red[2] + red[3];
    s2 = red[4] + red[5] + red[6] + red[7];
    float mu = s * (1.f / DMODEL);
    float var = s2 * (1.f / DMODEL) - mu * mu;
    float r = rsqrtf(var + LN_EPS);
    float c = ((v0 - mu) * r * g[tid] + bb[tid]) * hw[tid]
            + ((v1 - mu) * r * g[tid + 256] + bb[tid + 256]) * hw[tid + 256];
#pragma unroll
    for (int o = 32; o >= 1; o >>= 1) c += __shfl_xor(c, o);
    __syncthreads();
    if ((tid & 63) == 0) red[w] = c;
    __syncthreads();
    if (tid == 0) out[b] = red[0] + red[1] + red[2] + red[3] + hb[0];
}

// ---------------------------------------------------------------------------
extern "C" void kernel_launch(void* const* d_in, const int* in_sizes, int n_in,
                              void* d_out, int out_size, void* d_ws, size_t ws_size,
                              hipStream_t stream)
{
    const float* x      = (const float*)d_in[0];
    const float* W_in0  = (const float*)d_in[1];
    const float* b_in0  = (const float*)d_in[2];
    const float* W_in   = (const float*)d_in[3];
    const float* b_in   = (const float*)d_in[4];
    const float* A_log  = (const float*)d_in[5];
    const float* D_skip = (const float*)d_in[6];
    const float* W_dt   = (const float*)d_in[7];
    const float* b_dt   = (const float*)d_in[8];
    const float* W_B    = (const float*)d_in[9];
    const float* W_C    = (const float*)d_in[10];
    const float* ln_g   = (const float*)d_in[11];
    const float* ln_b   = (const float*)d_in[12];
    const float* head_w = (const float*)d_in[13];
    const float* head_b = (const float*)d_in[14];
    float* out = (float*)d_out;

    const size_t BLD = (size_t)B_SZ * L_SZ * DMODEL;         // 16.78M
    const size_t BLN = (size_t)B_SZ * L_SZ * DSTATE;         // 0.52M
    const size_t BCD = (size_t)B_SZ * NC * DMODEL * DSTATE;  // 4.19M
    const size_t XBN = (size_t)B_SZ * L_SZ * DIN;            // 2.10M

    // fp32 region (~55 MB), then bf16 region (~109 MB); total ~164 MB
    float* fp = (float*)d_ws;
    float* Bbuf  = fp; fp += BLN;
    float* Cbuf  = fp; fp += BLN;
    float* Pbuf  = fp; fp += BCD;
    float* Sbuf  = fp; fp += BCD;
    float* H0buf = fp; fp += BCD;
    float* ylast = fp; fp += (size_t)B_SZ * DMODEL;
    u16* hp = (u16*)fp;
    u16* xb   = hp; hp += XBN;
    u16* ub   = hp; hp += BLD;   // u bf16
    u16* dtb  = hp; hp += BLD;   // dt bf16
    u16* ybuf = hp; hp += BLD;   // layer output bf16 (next layer input)
    u16* WT0  = hp; hp += (size_t)DIN * DMODEL;
    u16* WTin = hp; hp += (size_t)(NLAYERS - 1) * DMODEL * DMODEL;
    u16* WTdt = hp; hp += (size_t)NLAYERS * DMODEL * DMODEL;
    u16* WBCT = hp; hp += (size_t)NLAYERS * 32 * DMODEL;

    const int M = B_SZ * L_SZ;   // 32768

    castx<<<(XBN / 4 + 255) / 256, 256, 0, stream>>>(x, xb, XBN / 4);
    wtrans<<<dim3(DIN / 32, DMODEL / 32, 1), 256, 0, stream>>>(W_in0, WT0, DIN, DMODEL);
    wtrans<<<dim3(DMODEL / 32, DMODEL / 32, NLAYERS - 1), 256, 0, stream>>>(W_in, WTin, DMODEL, DMODEL);
    wtrans<<<dim3(DMODEL / 32, DMODEL / 32, NLAYERS), 256, 0, stream>>>(W_dt, WTdt, DMODEL, DMODEL);
    prep_wbc<<<(NLAYERS * 32 * DMODEL) / 256, 256, 0, stream>>>(W_B, W_C, WBCT);

    for (int l = 0; l < NLAYERS; ++l) {
        const float* bu = (l == 0) ? b_in0 : b_in + (size_t)(l - 1) * DMODEL;

        if (l == 0) {
            gemm_mfma<0, 2, DIN><<<dim3(M / 128, DMODEL / 128), 256, 0, stream>>>(
                xb, WT0, bu, (float*)nullptr, ub, M, DMODEL);
        } else {
            gemm_mfma<0, 2, DMODEL><<<dim3(M / 128, DMODEL / 128), 256, 0, stream>>>(
                ybuf, WTin + (size_t)(l - 1) * DMODEL * DMODEL, bu,
                (float*)nullptr, ub, M, DMODEL);
        }
        gemm_mfma<1, 2, DMODEL><<<dim3(M / 128, DMODEL / 128), 256, 0, stream>>>(
            ub, WTdt + (size_t)l * DMODEL * DMODEL, b_dt + (size_t)l * DMODEL,
            (float*)nullptr, dtb, M, DMODEL);
        gemm_bc_mfma<<<M / 64, 256, 0, stream>>>(
            ub, WBCT + (size_t)l * 32 * DMODEL, Bbuf, Cbuf);
        const float* Al = A_log + (size_t)l * DMODEL * DSTATE;
        scan_pass1<<<dim3(DMODEL / 256, NC, B_SZ), 256, 0, stream>>>(
            ub, dtb, Bbuf, Al, Pbuf, Sbuf);
        scan_fix<<<(B_SZ * DMODEL * DSTATE) / 256, 256, 0, stream>>>(
            Pbuf, Sbuf, H0buf);
        scan_pass2<<<dim3(DMODEL / 256, NC, B_SZ), 256, 0, stream>>>(
            ub, dtb, Bbuf, Cbuf, Al, D_skip + (size_t)l * DMODEL,
            H0buf, ybuf, ylast);
    }

    ln_head_kernel<<<B_SZ, 256, 0, stream>>>(ylast, ln_g, ln_b, head_w, head_b, out);
}

// Round 8
// 762.497 us; speedup vs baseline: 6.9663x; 1.1822x over previous
//
#include <hip/hip_runtime.h>
#include <hip/hip_bf16.h>
#include <cstdint>
#include <cstddef>

#define B_SZ    16
#define L_SZ    2048
#define DIN     64
#define DMODEL  512
#define DSTATE  16
#define NLAYERS 4
#define LN_EPS  1e-5f
#define NC      32
#define TCH     (L_SZ / NC)   // 64
#define NFUSED  (2 * DMODEL)  // 1024

typedef __bf16 bf16x8 __attribute__((ext_vector_type(8)));
typedef float  f32x4  __attribute__((ext_vector_type(4)));
typedef unsigned short u16;
typedef unsigned int   u32;

__device__ __forceinline__ u16 f2bf(float f) {
    u32 u = __builtin_bit_cast(u32, f);
    u += 0x7fffu + ((u >> 16) & 1u);
    return (u16)(u >> 16);
}
__device__ __forceinline__ float bf2f(u16 v) {
    u32 u = ((u32)v) << 16;
    return __builtin_bit_cast(float, u);
}

// a_[n] = q^(n+1), n in [0,16): ~15 muls, shallow tree
__device__ __forceinline__ void pow16(float q, float* a_) {
    float q2 = q * q, q4 = q2 * q2, q8 = q4 * q4;
    a_[0] = q;        a_[1] = q2;       a_[2] = q2 * q;   a_[3] = q4;
    a_[4] = q4 * q;   a_[5] = q4 * q2;  a_[6] = a_[5] * q; a_[7] = q8;
    a_[8] = q8 * q;   a_[9] = q8 * q2;  a_[10] = a_[9] * q; a_[11] = q8 * q4;
    a_[12] = a_[11] * q; a_[13] = a_[11] * q2; a_[14] = a_[13] * q; a_[15] = q8 * q8;
}

#define LOG2E 1.4426950408889634f

__device__ __forceinline__ void gload16(const void* g, void* l) {
    __builtin_amdgcn_global_load_lds(
        (__attribute__((address_space(1))) void*)(g),
        (__attribute__((address_space(3))) void*)(l), 16, 0, 0);
}

// ---------------------------------------------------------------------------
// Fused u|dt bf16 MFMA GEMM, LDS double-buffered counted-vmcnt pipeline.
// [u | dt_arg] = A[M,K] @ BTcat[1024,K]^T + biascat.  128x128 tile, BK=64,
// 4 waves (2x2). Cols < 512 -> Cu plain; cols >= 512 -> softplus -> Cdt.
// Loads for tile k+1 stay in flight across barriers (vmcnt(8), never 0
// until the last tile).
// ---------------------------------------------------------------------------
template <int K>
__global__ __launch_bounds__(256) void gemm_fused(
    const u16* __restrict__ A, const u16* __restrict__ BT,
    const float* __restrict__ bias, u16* __restrict__ Cu,
    u16* __restrict__ Cdt, int M)
{
    constexpr int BM = 128, BK = 64;
    constexpr int NT = K / BK;
    __shared__ u16 As[2][BM * BK];   // 2 x 16 KB
    __shared__ u16 Bs[2][BM * BK];   // 2 x 16 KB  (total 64 KB)

    const int tid = threadIdx.x;
    const int wv = tid >> 6, ln = tid & 63;
    const int bm = blockIdx.x * BM, bn = blockIdx.y * BM;
    const int wm = (wv >> 1) * 64, wn = (wv & 1) * 64;

    f32x4 acc[4][4];
#pragma unroll
    for (int i = 0; i < 4; ++i)
#pragma unroll
        for (int j = 0; j < 4; ++j) acc[i][j] = (f32x4){0.f, 0.f, 0.f, 0.f};

    auto stage = [&](int buf, int k0) {
#pragma unroll
        for (int i = 0; i < 4; ++i) {
            int t = i * 256 + tid;
            int m = t >> 3, s = t & 7;
            int ksrc = (s ^ (m & 7)) * 8;           // pre-swizzled source chunk
            gload16(A + (size_t)(bm + m) * K + k0 + ksrc,
                    &As[buf][(i * 256 + wv * 64) * 8]);
            gload16(BT + (size_t)(bn + m) * K + k0 + ksrc,
                    &Bs[buf][(i * 256 + wv * 64) * 8]);
        }
    };

    stage(0, 0);
    if (NT > 1) stage(1, BK);

#pragma unroll
    for (int kt = 0; kt < NT; ++kt) {
        if (kt == NT - 1) asm volatile("s_waitcnt vmcnt(0)" ::: "memory");
        else              asm volatile("s_waitcnt vmcnt(8)" ::: "memory");
        __builtin_amdgcn_s_barrier();

        const int buf = kt & 1;
#pragma unroll
        for (int ks = 0; ks < 2; ++ks) {
            bf16x8 af[4], bfr[4];
            const int g = ln >> 4, lm = ln & 15;
            const int c = ks * 4 + g;
#pragma unroll
            for (int f = 0; f < 4; ++f) {
                int ml = wm + f * 16 + lm;
                af[f] = *(const bf16x8*)&As[buf][ml * 64 + ((c ^ (ml & 7)) * 8)];
                int nl = wn + f * 16 + lm;
                bfr[f] = *(const bf16x8*)&Bs[buf][nl * 64 + ((c ^ (nl & 7)) * 8)];
            }
#pragma unroll
            for (int fm = 0; fm < 4; ++fm)
#pragma unroll
                for (int fn = 0; fn < 4; ++fn)
                    acc[fm][fn] = __builtin_amdgcn_mfma_f32_16x16x32_bf16(
                        af[fm], bfr[fn], acc[fm][fn], 0, 0, 0);
        }

        asm volatile("s_waitcnt lgkmcnt(0)" ::: "memory");
        __builtin_amdgcn_s_barrier();
        if (kt + 2 < NT) stage(buf, (kt + 2) * BK);
    }

    // C/D layout: col=lane&15, row=(lane>>4)*4+reg  [verified m89/m91]
    const int cg = ln >> 4, lc = ln & 15;
    const bool uside = (bn < DMODEL);        // block-uniform
#pragma unroll
    for (int fm = 0; fm < 4; ++fm) {
#pragma unroll
        for (int fn = 0; fn < 4; ++fn) {
            int col = bn + wn + fn * 16 + lc;
            float bv = bias[col];
#pragma unroll
            for (int r = 0; r < 4; ++r) {
                int row = bm + wm + fm * 16 + cg * 4 + r;
                float v = acc[fm][fn][r] + bv;
                if (uside) {
                    Cu[(size_t)row * DMODEL + col] = f2bf(v);
                } else {
                    v = (v > 20.f) ? v : __logf(1.f + __expf(v));
                    Cdt[(size_t)row * DMODEL + (col - DMODEL)] = f2bf(v);
                }
            }
        }
    }
}

// ---------------------------------------------------------------------------
// Weight transpose + cast: WT[N][K] (bf16) from W[K][N] (f32). 32x32 tiles.
// ---------------------------------------------------------------------------
__global__ __launch_bounds__(256) void wtrans(
    const float* __restrict__ W, u16* __restrict__ WT, int K, int N)
{
    __shared__ float tile[32][33];
    int k0 = blockIdx.x * 32, n0 = blockIdx.y * 32;
    int tx = threadIdx.x & 31, ty = threadIdx.x >> 5;
#pragma unroll
    for (int i = 0; i < 4; ++i)
        tile[ty + 8 * i][tx] = W[(size_t)(k0 + ty + 8 * i) * N + n0 + tx];
    __syncthreads();
#pragma unroll
    for (int i = 0; i < 4; ++i)
        WT[(size_t)(n0 + ty + 8 * i) * K + k0 + tx] = f2bf(tile[tx][ty + 8 * i]);
}

// ---------------------------------------------------------------------------
// W_comboT[n][k] = sum_j W_dt[j][n] * W_in[k][j]   (bf16 out, f32 accum)
// grid (KD/16, 512/16); LDS-staged tiles.
// ---------------------------------------------------------------------------
__global__ __launch_bounds__(256) void wcombo(
    const float* __restrict__ Win,   // [KD][512]
    const float* __restrict__ Wdt,   // [512][512]
    u16* __restrict__ outT,          // [512][KD]
    int KD)
{
    __shared__ float wi[16][516];    // +4 pad: breaks 16-way bank alias
    __shared__ float wd[512][16];
    const int k0 = blockIdx.x * 16, n0 = blockIdx.y * 16;
    const int tid = threadIdx.x;
    for (int i = tid; i < 16 * 128; i += 256) {
        int r = i >> 7, c = i & 127;
        *(float4*)&wi[r][c * 4] =
            *(const float4*)&Win[(size_t)(k0 + r) * DMODEL + c * 4];
    }
    for (int i = tid; i < 512 * 4; i += 256) {
        int j = i >> 2, c = i & 3;
        *(float4*)&wd[j][c * 4] =
            *(const float4*)&Wdt[(size_t)j * DMODEL + n0 + c * 4];
    }
    __syncthreads();
    const int kk = tid & 15, nn = tid >> 4;
    float acc = 0.f;
#pragma unroll 8
    for (int j = 0; j < 512; ++j)
        acc = fmaf(wi[kk][j], wd[j][nn], acc);
    outT[(size_t)(n0 + nn) * KD + k0 + kk] = f2bf(acc);
}

// ---------------------------------------------------------------------------
// biascat[0:512) = b_in;  biascat[512+n] = b_dt[n] + sum_j b_in[j]*W_dt[j][n]
// grid = 4 blocks of 256.
// ---------------------------------------------------------------------------
__global__ __launch_bounds__(256) void biasprep(
    const float* __restrict__ bin, const float* __restrict__ Wdt,
    const float* __restrict__ bdt, float* __restrict__ biascat)
{
    int idx = blockIdx.x * 256 + threadIdx.x;
    if (idx < DMODEL) { biascat[idx] = bin[idx]; return; }
    int n = idx - DMODEL;
    float acc = bdt[n];
    for (int j = 0; j < DMODEL; ++j)
        acc = fmaf(bin[j], Wdt[(size_t)j * DMODEL + n], acc);
    biascat[idx] = acc;
}

// x -> bf16 cast
__global__ __launch_bounds__(256) void castx(
    const float* __restrict__ x, u16* __restrict__ xb, int n4)
{
    int i = blockIdx.x * 256 + threadIdx.x;
    if (i < n4) {
        float4 v = ((const float4*)x)[i];
        ushort4 o;
        o.x = f2bf(v.x); o.y = f2bf(v.y); o.z = f2bf(v.z); o.w = f2bf(v.w);
        ((ushort4*)xb)[i] = o;
    }
}

// ---------------------------------------------------------------------------
// Pack W_B,W_C ([L][512][16] f32) -> WBCT [L][32][512] bf16 (transposed).
// ---------------------------------------------------------------------------
__global__ __launch_bounds__(256) void prep_wbc(
    const float* __restrict__ WB, const float* __restrict__ WC,
    u16* __restrict__ WBCT)
{
    int idx = blockIdx.x * 256 + threadIdx.x;      // over NLAYERS*32*512
    int l = idx >> 14;                             // 32*512 = 16384
    int r = idx & 16383;
    int n = r >> 9, k = r & 511;
    float v = (n < 16) ? WB[((size_t)l * DMODEL + k) * DSTATE + n]
                       : WC[((size_t)l * DMODEL + k) * DSTATE + (n - 16)];
    WBCT[((size_t)l * 32 + n) * DMODEL + k] = f2bf(v);
}

// ---------------------------------------------------------------------------
// MFMA B/C projection: Bo/Co[M,16](f32) = u[M,512](bf16) @ {W_B,W_C}.
// ---------------------------------------------------------------------------
__global__ __launch_bounds__(256) void gemm_bc_mfma(
    const u16* __restrict__ A, const u16* __restrict__ WBCT,
    float* __restrict__ Bo, float* __restrict__ Co)
{
    const int tid = threadIdx.x;
    const int wv = tid >> 6, ln = tid & 63;
    const int m0 = blockIdx.x * 64 + wv * 16;
    const int g = ln >> 4, lm = ln & 15;

    f32x4 accB = (f32x4){0.f, 0.f, 0.f, 0.f};
    f32x4 accC = (f32x4){0.f, 0.f, 0.f, 0.f};
    const u16* arow = A + (size_t)(m0 + lm) * DMODEL;
    const u16* wb = WBCT + (size_t)lm * DMODEL;
    const u16* wc = WBCT + (size_t)(lm + 16) * DMODEL;
#pragma unroll
    for (int ks = 0; ks < DMODEL / 32; ++ks) {
        int ko = ks * 32 + g * 8;
        bf16x8 a = *(const bf16x8*)&arow[ko];
        bf16x8 b = *(const bf16x8*)&wb[ko];
        bf16x8 c = *(const bf16x8*)&wc[ko];
        accB = __builtin_amdgcn_mfma_f32_16x16x32_bf16(a, b, accB, 0, 0, 0);
        accC = __builtin_amdgcn_mfma_f32_16x16x32_bf16(a, c, accC, 0, 0, 0);
    }
#pragma unroll
    for (int r = 0; r < 4; ++r) {
        int m = m0 + g * 4 + r;
        Bo[(size_t)m * DSTATE + lm] = accB[r];
        Co[(size_t)m * DSTATE + lm] = accC[r];
    }
}

// ---------------------------------------------------------------------------
// Scan pass 1 (fast geometric path; fallback 16-exp loop).
// ---------------------------------------------------------------------------
__global__ __launch_bounds__(256) void scan_pass1(
    const u16* __restrict__ u, const u16* __restrict__ dt,
    const float* __restrict__ Bm, const float* __restrict__ A_log,
    float* __restrict__ P, float* __restrict__ S)
{
    const int tid = threadIdx.x;
    const int d = blockIdx.x * 256 + tid;
    const int c = blockIdx.y, b = blockIdx.z;
    __shared__ float Bs[TCH][DSTATE];

    const float* Bsrc = Bm + ((size_t)b * L_SZ + (size_t)c * TCH) * DSTATE;
    for (int i = tid; i < TCH * DSTATE / 4; i += 256)
        ((float4*)Bs)[i] = ((const float4*)Bsrc)[i];

    float Ac[16];
#pragma unroll
    for (int n = 0; n < 16; ++n) Ac[n] = -__expf(A_log[d * DSTATE + n]);
    bool geo = true;
#pragma unroll
    for (int n = 1; n < 16; ++n)
        geo &= fabsf(Ac[n] - (n + 1) * Ac[0]) <= 1e-4f * (n + 1) * fabsf(Ac[0]);
    __syncthreads();

    float s[16];
#pragma unroll
    for (int n = 0; n < 16; ++n) s[n] = 0.f;

    const size_t base = ((size_t)b * L_SZ + (size_t)c * TCH) * DMODEL + d;
    size_t o = (((size_t)b * NC + c) * DMODEL + d) * DSTATE;

    if (geo) {
        const float cK = Ac[0] * LOG2E;
        float qp = 1.f;
#pragma unroll 2
        for (int t = 0; t < TCH; ++t) {
            float dtv = bf2f(dt[base + (size_t)t * DMODEL]);
            float uv  = bf2f(u [base + (size_t)t * DMODEL]);
            float du = dtv * uv;
            float q = exp2f(dtv * cK);
            qp *= q;
            float a_[16];
            pow16(q, a_);
#pragma unroll
            for (int n = 0; n < 16; ++n)
                s[n] = fmaf(a_[n], s[n], du * Bs[t][n]);
        }
        float p_[16];
        pow16(qp, p_);
#pragma unroll
        for (int n = 0; n < 16; ++n) { P[o + n] = p_[n]; S[o + n] = s[n]; }
    } else {
        float p[16];
#pragma unroll
        for (int n = 0; n < 16; ++n) p[n] = 1.f;
#pragma unroll 2
        for (int t = 0; t < TCH; ++t) {
            float dtv = bf2f(dt[base + (size_t)t * DMODEL]);
            float uv  = bf2f(u [base + (size_t)t * DMODEL]);
            float du = dtv * uv;
#pragma unroll
            for (int n = 0; n < 16; ++n) {
                float a = __expf(dtv * Ac[n]);
                p[n] *= a;
                s[n] = fmaf(a, s[n], du * Bs[t][n]);
            }
        }
#pragma unroll
        for (int n = 0; n < 16; ++n) { P[o + n] = p[n]; S[o + n] = s[n]; }
    }
}

// ---------------------------------------------------------------------------
// Chunk fix-up: sequential over NC chunks per (b,d,n).
// ---------------------------------------------------------------------------
__global__ __launch_bounds__(256) void scan_fix(
    const float* __restrict__ P, const float* __restrict__ S,
    float* __restrict__ H0)
{
    const int idx = blockIdx.x * 256 + threadIdx.x;   // over B*D*N
    const int dn = idx & (DMODEL * DSTATE - 1);
    const int b = idx >> 13;                          // D*N = 8192
    float h = 0.f;
#pragma unroll
    for (int c = 0; c < NC; ++c) {
        size_t o = (((size_t)b * NC + c) << 13) + dn;
        H0[o] = h;
        h = fmaf(P[o], h, S[o]);
    }
}

// ---------------------------------------------------------------------------
// Scan pass 2: seeded with H0; emit y bf16 (+ fp32 last-token row).
// ---------------------------------------------------------------------------
__global__ __launch_bounds__(256) void scan_pass2(
    const u16* __restrict__ u, const u16* __restrict__ dt,
    const float* __restrict__ Bm, const float* __restrict__ Cm,
    const float* __restrict__ A_log, const float* __restrict__ Dskip,
    const float* __restrict__ H0, u16* __restrict__ yb,
    float* __restrict__ ylast)
{
    const int tid = threadIdx.x;
    const int d = blockIdx.x * 256 + tid;
    const int c = blockIdx.y, b = blockIdx.z;
    __shared__ float Bs[TCH][DSTATE];
    __shared__ float Cs[TCH][DSTATE];

    const float* Bsrc = Bm + ((size_t)b * L_SZ + (size_t)c * TCH) * DSTATE;
    const float* Csrc = Cm + ((size_t)b * L_SZ + (size_t)c * TCH) * DSTATE;
    for (int i = tid; i < TCH * DSTATE / 4; i += 256) {
        ((float4*)Bs)[i] = ((const float4*)Bsrc)[i];
        ((float4*)Cs)[i] = ((const float4*)Csrc)[i];
    }

    float Ac[16];
#pragma unroll
    for (int n = 0; n < 16; ++n) Ac[n] = -__expf(A_log[d * DSTATE + n]);
    bool geo = true;
#pragma unroll
    for (int n = 1; n < 16; ++n)
        geo &= fabsf(Ac[n] - (n + 1) * Ac[0]) <= 1e-4f * (n + 1) * fabsf(Ac[0]);
    const float Dk = Dskip[d];

    float h[16];
    size_t ho = (((size_t)b * NC + c) * DMODEL + d) * DSTATE;
#pragma unroll
    for (int n = 0; n < 16; ++n) h[n] = H0[ho + n];
    __syncthreads();

    const size_t base = ((size_t)b * L_SZ + (size_t)c * TCH) * DMODEL + d;

    if (geo) {
        const float cK = Ac[0] * LOG2E;
#pragma unroll 2
        for (int t = 0; t < TCH; ++t) {
            float dtv = bf2f(dt[base + (size_t)t * DMODEL]);
            float uv  = bf2f(u [base + (size_t)t * DMODEL]);
            float du = dtv * uv;
            float q = exp2f(dtv * cK);
            float a_[16];
            pow16(q, a_);
            float yv = 0.f;
#pragma unroll
            for (int n = 0; n < 16; ++n) {
                h[n] = fmaf(a_[n], h[n], du * Bs[t][n]);
                yv = fmaf(h[n], Cs[t][n], yv);
            }
            yv = fmaf(uv, Dk, yv);
            yb[base + (size_t)t * DMODEL] = f2bf(yv);
            if (c == NC - 1 && t == TCH - 1) ylast[(size_t)b * DMODEL + d] = yv;
        }
    } else {
#pragma unroll 2
        for (int t = 0; t < TCH; ++t) {
            float dtv = bf2f(dt[base + (size_t)t * DMODEL]);
            float uv  = bf2f(u [base + (size_t)t * DMODEL]);
            float du = dtv * uv;
            float yv = 0.f;
#pragma unroll
            for (int n = 0; n < 16; ++n) {
                float a = __expf(dtv * Ac[n]);
                h[n] = fmaf(a, h[n], du * Bs[t][n]);
                yv = fmaf(h[n], Cs[t][n], yv);
            }
            yv = fmaf(uv, Dk, yv);
            yb[base + (size_t)t * DMODEL] = f2bf(yv);
            if (c == NC - 1 && t == TCH - 1) ylast[(size_t)b * DMODEL + d] = yv;
        }
    }
}

// ---------------------------------------------------------------------------
// LayerNorm(last token) + head. One block per batch.
// ---------------------------------------------------------------------------
__global__ __launch_bounds__(256) void ln_head_kernel(
    const float* __restrict__ ylast, const float* __restrict__ g,
    const float* __restrict__ bb, const float* __restrict__ hw,
    const float* __restrict__ hb, float* __restrict__ out)
{
    const int b = blockIdx.x;
    const int tid = threadIdx.x;
    const float* row = ylast + (size_t)b * DMODEL;
    float v0 = row[tid], v1 = row[tid + 256];
    float s = v0 + v1;
    float s2 = v0 * v0 + v1 * v1;
#pragma unroll
    for (int o = 32; o >= 1; o >>= 1) {
        s += __shfl_xor(s, o);
        s2 += __shfl_xor(s2, o);
    }
    __shared__ float red[8];
    const int w = tid >> 6;
    if ((tid & 63) == 0) { red[w] = s; red[4 + w] = s2; }
    __syncthreads();
    s = red[0] + red[1] + red[2] + red[3];
    s2 = red[4] + red[5] + red[6] + red[7];
    float mu = s * (1.f / DMODEL);
    float var = s2 * (1.f / DMODEL) - mu * mu;
    float r = rsqrtf(var + LN_EPS);
    float c = ((v0 - mu) * r * g[tid] + bb[tid]) * hw[tid]
            + ((v1 - mu) * r * g[tid + 256] + bb[tid + 256]) * hw[tid + 256];
#pragma unroll
    for (int o = 32; o >= 1; o >>= 1) c += __shfl_xor(c, o);
    __syncthreads();
    if ((tid & 63) == 0) red[w] = c;
    __syncthreads();
    if (tid == 0) out[b] = red[0] + red[1] + red[2] + red[3] + hb[0];
}

// ---------------------------------------------------------------------------
extern "C" void kernel_launch(void* const* d_in, const int* in_sizes, int n_in,
                              void* d_out, int out_size, void* d_ws, size_t ws_size,
                              hipStream_t stream)
{
    const float* x      = (const float*)d_in[0];
    const float* W_in0  = (const float*)d_in[1];
    const float* b_in0  = (const float*)d_in[2];
    const float* W_in   = (const float*)d_in[3];
    const float* b_in   = (const float*)d_in[4];
    const float* A_log  = (const float*)d_in[5];
    const float* D_skip = (const float*)d_in[6];
    const float* W_dt   = (const float*)d_in[7];
    const float* b_dt   = (const float*)d_in[8];
    const float* W_B    = (const float*)d_in[9];
    const float* W_C    = (const float*)d_in[10];
    const float* ln_g   = (const float*)d_in[11];
    const float* ln_b   = (const float*)d_in[12];
    const float* head_w = (const float*)d_in[13];
    const float* head_b = (const float*)d_in[14];
    float* out = (float*)d_out;

    const size_t BLD = (size_t)B_SZ * L_SZ * DMODEL;         // 16.78M
    const size_t BLN = (size_t)B_SZ * L_SZ * DSTATE;         // 0.52M
    const size_t BCD = (size_t)B_SZ * NC * DMODEL * DSTATE;  // 4.19M
    const size_t XBN = (size_t)B_SZ * L_SZ * DIN;            // 2.10M

    // fp32 region (~55 MB) then bf16 region (~108 MB); total ~163 MB
    float* fp = (float*)d_ws;
    float* Bbuf  = fp; fp += BLN;
    float* Cbuf  = fp; fp += BLN;
    float* Pbuf  = fp; fp += BCD;
    float* Sbuf  = fp; fp += BCD;
    float* H0buf = fp; fp += BCD;
    float* ylast = fp; fp += (size_t)B_SZ * DMODEL;
    float* biascat = fp; fp += (size_t)NLAYERS * NFUSED;
    u16* hp = (u16*)fp;
    u16* xb    = hp; hp += XBN;
    u16* ub    = hp; hp += BLD;
    u16* dtb   = hp; hp += BLD;
    u16* ybuf  = hp; hp += BLD;
    u16* BT0   = hp; hp += (size_t)NFUSED * DIN;                    // layer 0
    u16* BTcat = hp; hp += (size_t)(NLAYERS - 1) * NFUSED * DMODEL; // layers 1-3
    u16* WBCT  = hp; hp += (size_t)NLAYERS * 32 * DMODEL;

    const int M = B_SZ * L_SZ;   // 32768

    // ---- prep ----
    castx<<<(XBN / 4 + 255) / 256, 256, 0, stream>>>(x, xb, XBN / 4);
    prep_wbc<<<(NLAYERS * 32 * DMODEL) / 256, 256, 0, stream>>>(W_B, W_C, WBCT);
    // layer 0: BT0 = [W_in0^T | (W_in0@W_dt0)^T]  (rows 1024, K=64)
    wtrans<<<dim3(DIN / 32, DMODEL / 32), 256, 0, stream>>>(W_in0, BT0, DIN, DMODEL);
    wcombo<<<dim3(DIN / 16, DMODEL / 16), 256, 0, stream>>>(
        W_in0, W_dt, BT0 + (size_t)DMODEL * DIN, DIN);
    biasprep<<<4, 256, 0, stream>>>(b_in0, W_dt, b_dt, biascat);
    for (int l = 1; l < NLAYERS; ++l) {
        u16* BTl = BTcat + (size_t)(l - 1) * NFUSED * DMODEL;
        const float* Wl = W_in + (size_t)(l - 1) * DMODEL * DMODEL;
        const float* Wd = W_dt + (size_t)l * DMODEL * DMODEL;
        wtrans<<<dim3(DMODEL / 32, DMODEL / 32), 256, 0, stream>>>(Wl, BTl, DMODEL, DMODEL);
        wcombo<<<dim3(DMODEL / 16, DMODEL / 16), 256, 0, stream>>>(
            Wl, Wd, BTl + (size_t)DMODEL * DMODEL, DMODEL);
        biasprep<<<4, 256, 0, stream>>>(
            b_in + (size_t)(l - 1) * DMODEL, Wd, b_dt + (size_t)l * DMODEL,
            biascat + (size_t)l * NFUSED);
    }

    // ---- layers ----
    for (int l = 0; l < NLAYERS; ++l) {
        if (l == 0) {
            gemm_fused<DIN><<<dim3(M / 128, NFUSED / 128), 256, 0, stream>>>(
                xb, BT0, biascat, ub, dtb, M);
        } else {
            gemm_fused<DMODEL><<<dim3(M / 128, NFUSED / 128), 256, 0, stream>>>(
                ybuf, BTcat + (size_t)(l - 1) * NFUSED * DMODEL,
                biascat + (size_t)l * NFUSED, ub, dtb, M);
        }
        gemm_bc_mfma<<<M / 64, 256, 0, stream>>>(
            ub, WBCT + (size_t)l * 32 * DMODEL, Bbuf, Cbuf);
        const float* Al = A_log + (size_t)l * DMODEL * DSTATE;
        scan_pass1<<<dim3(DMODEL / 256, NC, B_SZ), 256, 0, stream>>>(
            ub, dtb, Bbuf, Al, Pbuf, Sbuf);
        scan_fix<<<(B_SZ * DMODEL * DSTATE) / 256, 256, 0, stream>>>(
            Pbuf, Sbuf, H0buf);
        scan_pass2<<<dim3(DMODEL / 256, NC, B_SZ), 256, 0, stream>>>(
            ub, dtb, Bbuf, Cbuf, Al, D_skip + (size_t)l * DMODEL,
            H0buf, ybuf, ylast);
    }

    ln_head_kernel<<<B_SZ, 256, 0, stream>>>(ylast, ln_g, ln_b, head_w, head_b, out);
}

// Round 9
// 700.756 us; speedup vs baseline: 7.5801x; 1.0881x over previous
//
#include <hip/hip_runtime.h>
#include <hip/hip_bf16.h>
#include <cstdint>
#include <cstddef>

#define B_SZ    16
#define L_SZ    2048
#define DIN     64
#define DMODEL  512
#define DSTATE  16
#define NLAYERS 4
#define LN_EPS  1e-5f
#define NC      32
#define TCH     (L_SZ / NC)   // 64
#define NFUSED  (2 * DMODEL)  // 1024

typedef __bf16 bf16x8 __attribute__((ext_vector_type(8)));
typedef float  f32x4  __attribute__((ext_vector_type(4)));
typedef unsigned short u16;
typedef unsigned int   u32;

__device__ __forceinline__ u16 f2bf(float f) {
    u32 u = __builtin_bit_cast(u32, f);
    u += 0x7fffu + ((u >> 16) & 1u);
    return (u16)(u >> 16);
}
__device__ __forceinline__ float bf2f(u16 v) {
    u32 u = ((u32)v) << 16;
    return __builtin_bit_cast(float, u);
}

// a_[n] = q^(n+1), n in [0,16): ~15 muls, shallow tree
__device__ __forceinline__ void pow16(float q, float* a_) {
    float q2 = q * q, q4 = q2 * q2, q8 = q4 * q4;
    a_[0] = q;        a_[1] = q2;       a_[2] = q2 * q;   a_[3] = q4;
    a_[4] = q4 * q;   a_[5] = q4 * q2;  a_[6] = a_[5] * q; a_[7] = q8;
    a_[8] = q8 * q;   a_[9] = q8 * q2;  a_[10] = a_[9] * q; a_[11] = q8 * q4;
    a_[12] = a_[11] * q; a_[13] = a_[11] * q2; a_[14] = a_[13] * q; a_[15] = q8 * q8;
}

#define LOG2E 1.4426950408889634f

__device__ __forceinline__ void gload16(const void* g, void* l) {
    __builtin_amdgcn_global_load_lds(
        (__attribute__((address_space(1))) void*)(g),
        (__attribute__((address_space(3))) void*)(l), 16, 0, 0);
}

// ---------------------------------------------------------------------------
// Fused u|dt bf16 MFMA GEMM, 8 waves (512 thr), 128x128 tile, BK=64,
// LDS double-buffered counted-vmcnt pipeline. Wave tile 32x64 (2x4 frags).
// 1-D grid: bid = nb*256 + mb  ->  all 8 nb-blocks of one A-panel land on
// the same XCD (bid%8 == mb%8), so the A panel is fetched once per XCD.
// Cols < 512 -> Cu plain; cols >= 512 -> softplus -> Cdt.
// ---------------------------------------------------------------------------
template <int K>
__global__ __launch_bounds__(512) void gemm_fused(
    const u16* __restrict__ A, const u16* __restrict__ BT,
    const float* __restrict__ bias, u16* __restrict__ Cu,
    u16* __restrict__ Cdt, int M)
{
    constexpr int BM = 128, BK = 64;
    constexpr int NT = K / BK;
    __shared__ u16 As[2][BM * BK];   // 2 x 16 KB
    __shared__ u16 Bs[2][BM * BK];   // 2 x 16 KB  (total 64 KB)

    const int tid = threadIdx.x;
    const int wv = tid >> 6, ln = tid & 63;
    const int mb = blockIdx.x & 255, nb = blockIdx.x >> 8;
    const int bm = mb * BM, bn = nb * BM;
    const int wm = (wv >> 1) * 32, wn = (wv & 1) * 64;   // 4x2 wave grid

    f32x4 acc[2][4];
#pragma unroll
    for (int i = 0; i < 2; ++i)
#pragma unroll
        for (int j = 0; j < 4; ++j) acc[i][j] = (f32x4){0.f, 0.f, 0.f, 0.f};

    auto stage = [&](int buf, int k0) {
#pragma unroll
        for (int i = 0; i < 2; ++i) {
            int t = i * 512 + tid;
            int m = t >> 3, s = t & 7;
            int ksrc = (s ^ (m & 7)) * 8;           // pre-swizzled source chunk
            gload16(A + (size_t)(bm + m) * K + k0 + ksrc,
                    &As[buf][(i * 512 + wv * 64) * 8]);
            gload16(BT + (size_t)(bn + m) * K + k0 + ksrc,
                    &Bs[buf][(i * 512 + wv * 64) * 8]);
        }
    };

    stage(0, 0);
    if (NT > 1) stage(1, BK);

#pragma unroll
    for (int kt = 0; kt < NT; ++kt) {
        if (kt == NT - 1) asm volatile("s_waitcnt vmcnt(0)" ::: "memory");
        else              asm volatile("s_waitcnt vmcnt(4)" ::: "memory");
        __builtin_amdgcn_s_barrier();

        const int buf = kt & 1;
#pragma unroll
        for (int ks = 0; ks < 2; ++ks) {
            bf16x8 af[2], bfr[4];
            const int g = ln >> 4, lm = ln & 15;
            const int c = ks * 4 + g;
#pragma unroll
            for (int e = 0; e < 2; ++e) {
                int ml = wm + e * 16 + lm;
                af[e] = *(const bf16x8*)&As[buf][ml * 64 + ((c ^ (ml & 7)) * 8)];
            }
#pragma unroll
            for (int f = 0; f < 4; ++f) {
                int nl = wn + f * 16 + lm;
                bfr[f] = *(const bf16x8*)&Bs[buf][nl * 64 + ((c ^ (nl & 7)) * 8)];
            }
#pragma unroll
            for (int e = 0; e < 2; ++e)
#pragma unroll
                for (int f = 0; f < 4; ++f)
                    acc[e][f] = __builtin_amdgcn_mfma_f32_16x16x32_bf16(
                        af[e], bfr[f], acc[e][f], 0, 0, 0);
        }

        asm volatile("s_waitcnt lgkmcnt(0)" ::: "memory");
        __builtin_amdgcn_s_barrier();
        if (kt + 2 < NT) stage(buf, (kt + 2) * BK);
    }

    // C/D layout: col=lane&15, row=(lane>>4)*4+reg  [verified m89/m91]
    const int cg = ln >> 4, lc = ln & 15;
    const bool uside = (bn < DMODEL);        // block-uniform
#pragma unroll
    for (int e = 0; e < 2; ++e) {
#pragma unroll
        for (int f = 0; f < 4; ++f) {
            int col = bn + wn + f * 16 + lc;
            float bv = bias[col];
#pragma unroll
            for (int r = 0; r < 4; ++r) {
                int row = bm + wm + e * 16 + cg * 4 + r;
                float v = acc[e][f][r] + bv;
                if (uside) {
                    Cu[(size_t)row * DMODEL + col] = f2bf(v);
                } else {
                    v = (v > 20.f) ? v : __logf(1.f + __expf(v));
                    Cdt[(size_t)row * DMODEL + (col - DMODEL)] = f2bf(v);
                }
            }
        }
    }
}

// ---------------------------------------------------------------------------
// Weight transpose + cast with per-layer strides (z batched).
// ---------------------------------------------------------------------------
__global__ __launch_bounds__(256) void wtrans(
    const float* __restrict__ W, u16* __restrict__ WT, int K, int N,
    size_t inStride, size_t outStride)
{
    __shared__ float tile[32][33];
    const float* Wm = W + (size_t)blockIdx.z * inStride;
    u16* WTm = WT + (size_t)blockIdx.z * outStride;
    int k0 = blockIdx.x * 32, n0 = blockIdx.y * 32;
    int tx = threadIdx.x & 31, ty = threadIdx.x >> 5;
#pragma unroll
    for (int i = 0; i < 4; ++i)
        tile[ty + 8 * i][tx] = Wm[(size_t)(k0 + ty + 8 * i) * N + n0 + tx];
    __syncthreads();
#pragma unroll
    for (int i = 0; i < 4; ++i)
        WTm[(size_t)(n0 + ty + 8 * i) * K + k0 + tx] = f2bf(tile[tx][ty + 8 * i]);
}

// ---------------------------------------------------------------------------
// W_comboT[n][k] = sum_j W_dt[j][n] * W_in[k][j]  (bf16 out, f32 accum),
// z batched with strides.
// ---------------------------------------------------------------------------
__global__ __launch_bounds__(256) void wcombo(
    const float* __restrict__ Win, const float* __restrict__ Wdt,
    u16* __restrict__ outT, int KD,
    size_t winStride, size_t wdtStride, size_t outStride)
{
    __shared__ float wi[16][516];
    __shared__ float wd[512][16];
    const float* WinL = Win + (size_t)blockIdx.z * winStride;
    const float* WdtL = Wdt + (size_t)blockIdx.z * wdtStride;
    u16* outL = outT + (size_t)blockIdx.z * outStride;
    const int k0 = blockIdx.x * 16, n0 = blockIdx.y * 16;
    const int tid = threadIdx.x;
    for (int i = tid; i < 16 * 128; i += 256) {
        int r = i >> 7, c = i & 127;
        *(float4*)&wi[r][c * 4] =
            *(const float4*)&WinL[(size_t)(k0 + r) * DMODEL + c * 4];
    }
    for (int i = tid; i < 512 * 4; i += 256) {
        int j = i >> 2, c = i & 3;
        *(float4*)&wd[j][c * 4] =
            *(const float4*)&WdtL[(size_t)j * DMODEL + n0 + c * 4];
    }
    __syncthreads();
    const int kk = tid & 15, nn = tid >> 4;
    float acc = 0.f;
#pragma unroll 8
    for (int j = 0; j < 512; ++j)
        acc = fmaf(wi[kk][j], wd[j][nn], acc);
    outL[(size_t)(n0 + nn) * KD + k0 + kk] = f2bf(acc);
}

// ---------------------------------------------------------------------------
// biascat[0:512) = b_in; biascat[512+n] = b_dt[n] + sum_j b_in[j]*W_dt[j][n]
// z batched with strides.
// ---------------------------------------------------------------------------
__global__ __launch_bounds__(256) void biasprep(
    const float* __restrict__ bin, const float* __restrict__ Wdt,
    const float* __restrict__ bdt, float* __restrict__ biascat,
    size_t binStride, size_t wdtStride, size_t bdtStride, size_t outStride)
{
    const float* binL = bin + (size_t)blockIdx.z * binStride;
    const float* WdtL = Wdt + (size_t)blockIdx.z * wdtStride;
    const float* bdtL = bdt + (size_t)blockIdx.z * bdtStride;
    float* outL = biascat + (size_t)blockIdx.z * outStride;
    int idx = blockIdx.x * 256 + threadIdx.x;
    if (idx < DMODEL) { outL[idx] = binL[idx]; return; }
    int n = idx - DMODEL;
    float acc = bdtL[n];
    for (int j = 0; j < DMODEL; ++j)
        acc = fmaf(binL[j], WdtL[(size_t)j * DMODEL + n], acc);
    outL[idx] = acc;
}

// x -> bf16 cast
__global__ __launch_bounds__(256) void castx(
    const float* __restrict__ x, u16* __restrict__ xb, int n4)
{
    int i = blockIdx.x * 256 + threadIdx.x;
    if (i < n4) {
        float4 v = ((const float4*)x)[i];
        ushort4 o;
        o.x = f2bf(v.x); o.y = f2bf(v.y); o.z = f2bf(v.z); o.w = f2bf(v.w);
        ((ushort4*)xb)[i] = o;
    }
}

// ---------------------------------------------------------------------------
// Pack W_B,W_C ([L][512][16] f32) -> WBCT [L][32][512] bf16 (transposed).
// ---------------------------------------------------------------------------
__global__ __launch_bounds__(256) void prep_wbc(
    const float* __restrict__ WB, const float* __restrict__ WC,
    u16* __restrict__ WBCT)
{
    int idx = blockIdx.x * 256 + threadIdx.x;      // over NLAYERS*32*512
    int l = idx >> 14;                             // 32*512 = 16384
    int r = idx & 16383;
    int n = r >> 9, k = r & 511;
    float v = (n < 16) ? WB[((size_t)l * DMODEL + k) * DSTATE + n]
                       : WC[((size_t)l * DMODEL + k) * DSTATE + (n - 16)];
    WBCT[((size_t)l * 32 + n) * DMODEL + k] = f2bf(v);
}

// ---------------------------------------------------------------------------
// MFMA B/C projection: Bo/Co[M,16](f32) = u[M,512](bf16) @ {W_B,W_C}.
// ---------------------------------------------------------------------------
__global__ __launch_bounds__(256) void gemm_bc_mfma(
    const u16* __restrict__ A, const u16* __restrict__ WBCT,
    float* __restrict__ Bo, float* __restrict__ Co)
{
    const int tid = threadIdx.x;
    const int wv = tid >> 6, ln = tid & 63;
    const int m0 = blockIdx.x * 64 + wv * 16;
    const int g = ln >> 4, lm = ln & 15;

    f32x4 accB = (f32x4){0.f, 0.f, 0.f, 0.f};
    f32x4 accC = (f32x4){0.f, 0.f, 0.f, 0.f};
    const u16* arow = A + (size_t)(m0 + lm) * DMODEL;
    const u16* wb = WBCT + (size_t)lm * DMODEL;
    const u16* wc = WBCT + (size_t)(lm + 16) * DMODEL;
#pragma unroll
    for (int ks = 0; ks < DMODEL / 32; ++ks) {
        int ko = ks * 32 + g * 8;
        bf16x8 a = *(const bf16x8*)&arow[ko];
        bf16x8 b = *(const bf16x8*)&wb[ko];
        bf16x8 c = *(const bf16x8*)&wc[ko];
        accB = __builtin_amdgcn_mfma_f32_16x16x32_bf16(a, b, accB, 0, 0, 0);
        accC = __builtin_amdgcn_mfma_f32_16x16x32_bf16(a, c, accC, 0, 0, 0);
    }
#pragma unroll
    for (int r = 0; r < 4; ++r) {
        int m = m0 + g * 4 + r;
        Bo[(size_t)m * DSTATE + lm] = accB[r];
        Co[(size_t)m * DSTATE + lm] = accC[r];
    }
}

// ---------------------------------------------------------------------------
// Scan pass 1 (fast geometric path; fallback 16-exp loop).
// ---------------------------------------------------------------------------
__global__ __launch_bounds__(256) void scan_pass1(
    const u16* __restrict__ u, const u16* __restrict__ dt,
    const float* __restrict__ Bm, const float* __restrict__ A_log,
    float* __restrict__ P, float* __restrict__ S)
{
    const int tid = threadIdx.x;
    const int d = blockIdx.x * 256 + tid;
    const int c = blockIdx.y, b = blockIdx.z;
    __shared__ float Bs[TCH][DSTATE];

    const float* Bsrc = Bm + ((size_t)b * L_SZ + (size_t)c * TCH) * DSTATE;
    for (int i = tid; i < TCH * DSTATE / 4; i += 256)
        ((float4*)Bs)[i] = ((const float4*)Bsrc)[i];

    float Ac[16];
#pragma unroll
    for (int n = 0; n < 16; ++n) Ac[n] = -__expf(A_log[d * DSTATE + n]);
    bool geo = true;
#pragma unroll
    for (int n = 1; n < 16; ++n)
        geo &= fabsf(Ac[n] - (n + 1) * Ac[0]) <= 1e-4f * (n + 1) * fabsf(Ac[0]);
    __syncthreads();

    float s[16];
#pragma unroll
    for (int n = 0; n < 16; ++n) s[n] = 0.f;

    const size_t base = ((size_t)b * L_SZ + (size_t)c * TCH) * DMODEL + d;
    size_t o = (((size_t)b * NC + c) * DMODEL + d) * DSTATE;

    if (geo) {
        const float cK = Ac[0] * LOG2E;
        float qp = 1.f;
#pragma unroll 2
        for (int t = 0; t < TCH; ++t) {
            float dtv = bf2f(dt[base + (size_t)t * DMODEL]);
            float uv  = bf2f(u [base + (size_t)t * DMODEL]);
            float du = dtv * uv;
            float q = exp2f(dtv * cK);
            qp *= q;
            float a_[16];
            pow16(q, a_);
#pragma unroll
            for (int n = 0; n < 16; ++n)
                s[n] = fmaf(a_[n], s[n], du * Bs[t][n]);
        }
        float p_[16];
        pow16(qp, p_);
#pragma unroll
        for (int n = 0; n < 16; ++n) { P[o + n] = p_[n]; S[o + n] = s[n]; }
    } else {
        float p[16];
#pragma unroll
        for (int n = 0; n < 16; ++n) p[n] = 1.f;
#pragma unroll 2
        for (int t = 0; t < TCH; ++t) {
            float dtv = bf2f(dt[base + (size_t)t * DMODEL]);
            float uv  = bf2f(u [base + (size_t)t * DMODEL]);
            float du = dtv * uv;
#pragma unroll
            for (int n = 0; n < 16; ++n) {
                float a = __expf(dtv * Ac[n]);
                p[n] *= a;
                s[n] = fmaf(a, s[n], du * Bs[t][n]);
            }
        }
#pragma unroll
        for (int n = 0; n < 16; ++n) { P[o + n] = p[n]; S[o + n] = s[n]; }
    }
}

// ---------------------------------------------------------------------------
// Chunk fix-up: sequential over NC chunks per (b,d,n).
// ---------------------------------------------------------------------------
__global__ __launch_bounds__(256) void scan_fix(
    const float* __restrict__ P, const float* __restrict__ S,
    float* __restrict__ H0)
{
    const int idx = blockIdx.x * 256 + threadIdx.x;   // over B*D*N
    const int dn = idx & (DMODEL * DSTATE - 1);
    const int b = idx >> 13;                          // D*N = 8192
    float h = 0.f;
#pragma unroll
    for (int c = 0; c < NC; ++c) {
        size_t o = (((size_t)b * NC + c) << 13) + dn;
        H0[o] = h;
        h = fmaf(P[o], h, S[o]);
    }
}

// ---------------------------------------------------------------------------
// Scan pass 2: seeded with H0; emit y bf16 (+ fp32 last-token row).
// ---------------------------------------------------------------------------
__global__ __launch_bounds__(256) void scan_pass2(
    const u16* __restrict__ u, const u16* __restrict__ dt,
    const float* __restrict__ Bm, const float* __restrict__ Cm,
    const float* __restrict__ A_log, const float* __restrict__ Dskip,
    const float* __restrict__ H0, u16* __restrict__ yb,
    float* __restrict__ ylast)
{
    const int tid = threadIdx.x;
    const int d = blockIdx.x * 256 + tid;
    const int c = blockIdx.y, b = blockIdx.z;
    __shared__ float Bs[TCH][DSTATE];
    __shared__ float Cs[TCH][DSTATE];

    const float* Bsrc = Bm + ((size_t)b * L_SZ + (size_t)c * TCH) * DSTATE;
    const float* Csrc = Cm + ((size_t)b * L_SZ + (size_t)c * TCH) * DSTATE;
    for (int i = tid; i < TCH * DSTATE / 4; i += 256) {
        ((float4*)Bs)[i] = ((const float4*)Bsrc)[i];
        ((float4*)Cs)[i] = ((const float4*)Csrc)[i];
    }

    float Ac[16];
#pragma unroll
    for (int n = 0; n < 16; ++n) Ac[n] = -__expf(A_log[d * DSTATE + n]);
    bool geo = true;
#pragma unroll
    for (int n = 1; n < 16; ++n)
        geo &= fabsf(Ac[n] - (n + 1) * Ac[0]) <= 1e-4f * (n + 1) * fabsf(Ac[0]);
    const float Dk = Dskip[d];

    float h[16];
    size_t ho = (((size_t)b * NC + c) * DMODEL + d) * DSTATE;
#pragma unroll
    for (int n = 0; n < 16; ++n) h[n] = H0[ho + n];
    __syncthreads();

    const size_t base = ((size_t)b * L_SZ + (size_t)c * TCH) * DMODEL + d;

    if (geo) {
        const float cK = Ac[0] * LOG2E;
#pragma unroll 2
        for (int t = 0; t < TCH; ++t) {
            float dtv = bf2f(dt[base + (size_t)t * DMODEL]);
            float uv  = bf2f(u [base + (size_t)t * DMODEL]);
            float du = dtv * uv;
            float q = exp2f(dtv * cK);
            float a_[16];
            pow16(q, a_);
            float yv = 0.f;
#pragma unroll
            for (int n = 0; n < 16; ++n) {
                h[n] = fmaf(a_[n], h[n], du * Bs[t][n]);
                yv = fmaf(h[n], Cs[t][n], yv);
            }
            yv = fmaf(uv, Dk, yv);
            yb[base + (size_t)t * DMODEL] = f2bf(yv);
            if (c == NC - 1 && t == TCH - 1) ylast[(size_t)b * DMODEL + d] = yv;
        }
    } else {
#pragma unroll 2
        for (int t = 0; t < TCH; ++t) {
            float dtv = bf2f(dt[base + (size_t)t * DMODEL]);
            float uv  = bf2f(u [base + (size_t)t * DMODEL]);
            float du = dtv * uv;
            float yv = 0.f;
#pragma unroll
            for (int n = 0; n < 16; ++n) {
                float a = __expf(dtv * Ac[n]);
                h[n] = fmaf(a, h[n], du * Bs[t][n]);
                yv = fmaf(h[n], Cs[t][n], yv);
            }
            yv = fmaf(uv, Dk, yv);
            yb[base + (size_t)t * DMODEL] = f2bf(yv);
            if (c == NC - 1 && t == TCH - 1) ylast[(size_t)b * DMODEL + d] = yv;
        }
    }
}

// ---------------------------------------------------------------------------
// LayerNorm(last token) + head. One block per batch.
// ---------------------------------------------------------------------------
__global__ __launch_bounds__(256) void ln_head_kernel(
    const float* __restrict__ ylast, const float* __restrict__ g,
    const float* __restrict__ bb, const float* __restrict__ hw,
    const float* __restrict__ hb, float* __restrict__ out)
{
    const int b = blockIdx.x;
    const int tid = threadIdx.x;
    const float* row = ylast + (size_t)b * DMODEL;
    float v0 = row[tid], v1 = row[tid + 256];
    float s = v0 + v1;
    float s2 = v0 * v0 + v1 * v1;
#pragma unroll
    for (int o = 32; o >= 1; o >>= 1) {
        s += __shfl_xor(s, o);
        s2 += __shfl_xor(s2, o);
    }
    __shared__ float red[8];
    const int w = tid >> 6;
    if ((tid & 63) == 0) { red[w] = s; red[4 + w] = s2; }
    __syncthreads();
    s = red[0] + red[1] + red[2] + red[3];
    s2 = red[4] + red[5] + red[6] + red[7];
    float mu = s * (1.f / DMODEL);
    float var = s2 * (1.f / DMODEL) - mu * mu;
    float r = rsqrtf(var + LN_EPS);
    float c = ((v0 - mu) * r * g[tid] + bb[tid]) * hw[tid]
            + ((v1 - mu) * r * g[tid + 256] + bb[tid + 256]) * hw[tid + 256];
#pragma unroll
    for (int o = 32; o >= 1; o >>= 1) c += __shfl_xor(c, o);
    __syncthreads();
    if ((tid & 63) == 0) red[w] = c;
    __syncthreads();
    if (tid == 0) out[b] = red[0] + red[1] + red[2] + red[3] + hb[0];
}

// ---------------------------------------------------------------------------
extern "C" void kernel_launch(void* const* d_in, const int* in_sizes, int n_in,
                              void* d_out, int out_size, void* d_ws, size_t ws_size,
                              hipStream_t stream)
{
    const float* x      = (const float*)d_in[0];
    const float* W_in0  = (const float*)d_in[1];
    const float* b_in0  = (const float*)d_in[2];
    const float* W_in   = (const float*)d_in[3];
    const float* b_in   = (const float*)d_in[4];
    const float* A_log  = (const float*)d_in[5];
    const float* D_skip = (const float*)d_in[6];
    const float* W_dt   = (const float*)d_in[7];
    const float* b_dt   = (const float*)d_in[8];
    const float* W_B    = (const float*)d_in[9];
    const float* W_C    = (const float*)d_in[10];
    const float* ln_g   = (const float*)d_in[11];
    const float* ln_b   = (const float*)d_in[12];
    const float* head_w = (const float*)d_in[13];
    const float* head_b = (const float*)d_in[14];
    float* out = (float*)d_out;

    const size_t BLD = (size_t)B_SZ * L_SZ * DMODEL;         // 16.78M
    const size_t BLN = (size_t)B_SZ * L_SZ * DSTATE;         // 0.52M
    const size_t BCD = (size_t)B_SZ * NC * DMODEL * DSTATE;  // 4.19M
    const size_t XBN = (size_t)B_SZ * L_SZ * DIN;            // 2.10M

    float* fp = (float*)d_ws;
    float* Bbuf  = fp; fp += BLN;
    float* Cbuf  = fp; fp += BLN;
    float* Pbuf  = fp; fp += BCD;
    float* Sbuf  = fp; fp += BCD;
    float* H0buf = fp; fp += BCD;
    float* ylast = fp; fp += (size_t)B_SZ * DMODEL;
    float* biascat = fp; fp += (size_t)NLAYERS * NFUSED;
    u16* hp = (u16*)fp;
    u16* xb    = hp; hp += XBN;
    u16* ub    = hp; hp += BLD;
    u16* dtb   = hp; hp += BLD;
    u16* ybuf  = hp; hp += BLD;
    u16* BT0   = hp; hp += (size_t)NFUSED * DIN;                    // layer 0
    u16* BTcat = hp; hp += (size_t)(NLAYERS - 1) * NFUSED * DMODEL; // layers 1-3
    u16* WBCT  = hp; hp += (size_t)NLAYERS * 32 * DMODEL;

    const int M = B_SZ * L_SZ;   // 32768

    // ---- prep ----
    castx<<<(XBN / 4 + 255) / 256, 256, 0, stream>>>(x, xb, XBN / 4);
    prep_wbc<<<(NLAYERS * 32 * DMODEL) / 256, 256, 0, stream>>>(W_B, W_C, WBCT);
    // layer 0: BT0 = [W_in0^T | (W_in0@W_dt0)^T]  (1024 rows, K=64)
    wtrans<<<dim3(DIN / 32, DMODEL / 32, 1), 256, 0, stream>>>(
        W_in0, BT0, DIN, DMODEL, 0, 0);
    wcombo<<<dim3(DIN / 16, DMODEL / 16, 1), 256, 0, stream>>>(
        W_in0, W_dt, BT0 + (size_t)DMODEL * DIN, DIN, 0, 0, 0);
    biasprep<<<dim3(4, 1, 1), 256, 0, stream>>>(
        b_in0, W_dt, b_dt, biascat, 0, 0, 0, 0);
    // layers 1-3 batched over z
    wtrans<<<dim3(DMODEL / 32, DMODEL / 32, NLAYERS - 1), 256, 0, stream>>>(
        W_in, BTcat, DMODEL, DMODEL,
        (size_t)DMODEL * DMODEL, (size_t)NFUSED * DMODEL);
    wcombo<<<dim3(DMODEL / 16, DMODEL / 16, NLAYERS - 1), 256, 0, stream>>>(
        W_in, W_dt + (size_t)DMODEL * DMODEL,
        BTcat + (size_t)DMODEL * DMODEL, DMODEL,
        (size_t)DMODEL * DMODEL, (size_t)DMODEL * DMODEL,
        (size_t)NFUSED * DMODEL);
    biasprep<<<dim3(4, 1, NLAYERS - 1), 256, 0, stream>>>(
        b_in, W_dt + (size_t)DMODEL * DMODEL, b_dt + DMODEL, biascat + NFUSED,
        DMODEL, (size_t)DMODEL * DMODEL, DMODEL, NFUSED);

    // ---- layers ----
    for (int l = 0; l < NLAYERS; ++l) {
        if (l == 0) {
            gemm_fused<DIN><<<(M / 128) * (NFUSED / 128), 512, 0, stream>>>(
                xb, BT0, biascat, ub, dtb, M);
        } else {
            gemm_fused<DMODEL><<<(M / 128) * (NFUSED / 128), 512, 0, stream>>>(
                ybuf, BTcat + (size_t)(l - 1) * NFUSED * DMODEL,
                biascat + (size_t)l * NFUSED, ub, dtb, M);
        }
        gemm_bc_mfma<<<M / 64, 256, 0, stream>>>(
            ub, WBCT + (size_t)l * 32 * DMODEL, Bbuf, Cbuf);
        const float* Al = A_log + (size_t)l * DMODEL * DSTATE;
        scan_pass1<<<dim3(DMODEL / 256, NC, B_SZ), 256, 0, stream>>>(
            ub, dtb, Bbuf, Al, Pbuf, Sbuf);
        scan_fix<<<(B_SZ * DMODEL * DSTATE) / 256, 256, 0, stream>>>(
            Pbuf, Sbuf, H0buf);
        scan_pass2<<<dim3(DMODEL / 256, NC, B_SZ), 256, 0, stream>>>(
            ub, dtb, Bbuf, Cbuf, Al, D_skip + (size_t)l * DMODEL,
            H0buf, ybuf, ylast);
    }

    ln_head_kernel<<<B_SZ, 256, 0, stream>>>(ylast, ln_g, ln_b, head_w, head_b, out);
}

// Round 10
// 693.371 us; speedup vs baseline: 7.6609x; 1.0107x over previous
//
#include <hip/hip_runtime.h>
#include <hip/hip_bf16.h>
#include <cstdint>
#include <cstddef>

#define B_SZ    16
#define L_SZ    2048
#define DIN     64
#define DMODEL  512
#define DSTATE  16
#define NLAYERS 4
#define LN_EPS  1e-5f
#define NC      32
#define TCH     (L_SZ / NC)   // 64
#define NFUSED  (2 * DMODEL)  // 1024

typedef __bf16 bf16x8 __attribute__((ext_vector_type(8)));
typedef float  f32x4  __attribute__((ext_vector_type(4)));
typedef unsigned short u16;
typedef unsigned int   u32;

__device__ __forceinline__ u16 f2bf(float f) {
    u32 u = __builtin_bit_cast(u32, f);
    u += 0x7fffu + ((u >> 16) & 1u);
    return (u16)(u >> 16);
}
__device__ __forceinline__ float bf2f(u16 v) {
    u32 u = ((u32)v) << 16;
    return __builtin_bit_cast(float, u);
}

// a_[n] = q^(n+1), n in [0,16): ~15 muls, shallow tree
__device__ __forceinline__ void pow16(float q, float* a_) {
    float q2 = q * q, q4 = q2 * q2, q8 = q4 * q4;
    a_[0] = q;        a_[1] = q2;       a_[2] = q2 * q;   a_[3] = q4;
    a_[4] = q4 * q;   a_[5] = q4 * q2;  a_[6] = a_[5] * q; a_[7] = q8;
    a_[8] = q8 * q;   a_[9] = q8 * q2;  a_[10] = a_[9] * q; a_[11] = q8 * q4;
    a_[12] = a_[11] * q; a_[13] = a_[11] * q2; a_[14] = a_[13] * q; a_[15] = q8 * q8;
}

#define LOG2E 1.4426950408889634f

__device__ __forceinline__ void gload16(const void* g, void* l) {
    __builtin_amdgcn_global_load_lds(
        (__attribute__((address_space(1))) void*)(g),
        (__attribute__((address_space(3))) void*)(l), 16, 0, 0);
}

// ---------------------------------------------------------------------------
// Fused u|dt bf16 MFMA GEMM, 8 waves (512 thr), 128x128 tile, BK=32.
// LDS = 2buf x (A+B) x 8KB = 32 KB -> 4 blocks/CU x 8 waves = 8 waves/SIMD.
// Counted-vmcnt double buffer: each thread stages exactly 2 chunks per
// K-tile (1 A + 1 B); wait vmcnt(2) keeps next tile's loads in flight.
// Swizzle: stage ksrc = (s ^ ((m>>1)&3))*8, read slot g ^ ((ml>>1)&3)
// -> 8 banks x 2 lanes on ds_read_b128 (2-way = free).
// 1-D grid bid = nb*256 + mb -> bid%8 == mb%8: the 8 nb-blocks sharing an
// A-panel land on one XCD. Cols < 512 -> Cu; cols >= 512 -> softplus -> Cdt.
// ---------------------------------------------------------------------------
template <int K>
__global__ __launch_bounds__(512) void gemm_fused(
    const u16* __restrict__ A, const u16* __restrict__ BT,
    const float* __restrict__ bias, u16* __restrict__ Cu,
    u16* __restrict__ Cdt, int M)
{
    constexpr int BM = 128, BK = 32;
    constexpr int NT = K / BK;
    __shared__ u16 As[2][BM * BK];   // 2 x 8 KB
    __shared__ u16 Bs[2][BM * BK];   // 2 x 8 KB  (total 32 KB)

    const int tid = threadIdx.x;
    const int wv = tid >> 6, ln = tid & 63;
    const int mb = blockIdx.x & 255, nb = blockIdx.x >> 8;
    const int bm = mb * BM, bn = nb * BM;
    const int wm = (wv >> 1) * 32, wn = (wv & 1) * 64;   // 4x2 wave grid

    f32x4 acc[2][4];
#pragma unroll
    for (int i = 0; i < 2; ++i)
#pragma unroll
        for (int j = 0; j < 4; ++j) acc[i][j] = (f32x4){0.f, 0.f, 0.f, 0.f};

    // one 128x32 A-tile + B-tile: 512 chunks each -> 1 A + 1 B load/thread
    const int sm = tid >> 2, ss = tid & 3;
    const int ksrc = (ss ^ ((sm >> 1) & 3)) * 8;        // pre-swizzled source
    auto stage = [&](int buf, int k0) {
        gload16(A + (size_t)(bm + sm) * K + k0 + ksrc, &As[buf][(wv * 64) * 8]);
        gload16(BT + (size_t)(bn + sm) * K + k0 + ksrc, &Bs[buf][(wv * 64) * 8]);
    };

    stage(0, 0);
    if (NT > 1) stage(1, BK);

#pragma unroll
    for (int kt = 0; kt < NT; ++kt) {
        if (kt == NT - 1) asm volatile("s_waitcnt vmcnt(0)" ::: "memory");
        else              asm volatile("s_waitcnt vmcnt(2)" ::: "memory");
        __builtin_amdgcn_s_barrier();

        const int buf = kt & 1;
        const int g = ln >> 4, lm = ln & 15;
        bf16x8 af[2], bfr[4];
#pragma unroll
        for (int e = 0; e < 2; ++e) {
            int ml = wm + e * 16 + lm;
            af[e] = *(const bf16x8*)&As[buf][ml * 32 + ((g ^ ((ml >> 1) & 3)) * 8)];
        }
#pragma unroll
        for (int f = 0; f < 4; ++f) {
            int nl = wn + f * 16 + lm;
            bfr[f] = *(const bf16x8*)&Bs[buf][nl * 32 + ((g ^ ((nl >> 1) & 3)) * 8)];
        }
#pragma unroll
        for (int e = 0; e < 2; ++e)
#pragma unroll
            for (int f = 0; f < 4; ++f)
                acc[e][f] = __builtin_amdgcn_mfma_f32_16x16x32_bf16(
                    af[e], bfr[f], acc[e][f], 0, 0, 0);

        asm volatile("s_waitcnt lgkmcnt(0)" ::: "memory");
        __builtin_amdgcn_s_barrier();
        if (kt + 2 < NT) stage(buf, (kt + 2) * BK);
    }

    // C/D layout: col=lane&15, row=(lane>>4)*4+reg  [verified m89/m91]
    const int cg = ln >> 4, lc = ln & 15;
    const bool uside = (bn < DMODEL);        // block-uniform
#pragma unroll
    for (int e = 0; e < 2; ++e) {
#pragma unroll
        for (int f = 0; f < 4; ++f) {
            int col = bn + wn + f * 16 + lc;
            float bv = bias[col];
#pragma unroll
            for (int r = 0; r < 4; ++r) {
                int row = bm + wm + e * 16 + cg * 4 + r;
                float v = acc[e][f][r] + bv;
                if (uside) {
                    Cu[(size_t)row * DMODEL + col] = f2bf(v);
                } else {
                    v = (v > 20.f) ? v : __logf(1.f + __expf(v));
                    Cdt[(size_t)row * DMODEL + (col - DMODEL)] = f2bf(v);
                }
            }
        }
    }
}

// ---------------------------------------------------------------------------
// Weight transpose + cast with per-layer strides (z batched).
// ---------------------------------------------------------------------------
__global__ __launch_bounds__(256) void wtrans(
    const float* __restrict__ W, u16* __restrict__ WT, int K, int N,
    size_t inStride, size_t outStride)
{
    __shared__ float tile[32][33];
    const float* Wm = W + (size_t)blockIdx.z * inStride;
    u16* WTm = WT + (size_t)blockIdx.z * outStride;
    int k0 = blockIdx.x * 32, n0 = blockIdx.y * 32;
    int tx = threadIdx.x & 31, ty = threadIdx.x >> 5;
#pragma unroll
    for (int i = 0; i < 4; ++i)
        tile[ty + 8 * i][tx] = Wm[(size_t)(k0 + ty + 8 * i) * N + n0 + tx];
    __syncthreads();
#pragma unroll
    for (int i = 0; i < 4; ++i)
        WTm[(size_t)(n0 + ty + 8 * i) * K + k0 + tx] = f2bf(tile[tx][ty + 8 * i]);
}

// ---------------------------------------------------------------------------
// W_comboT[n][k] = sum_j W_dt[j][n] * W_in[k][j]  (bf16 out, f32 accum),
// z batched with strides.
// ---------------------------------------------------------------------------
__global__ __launch_bounds__(256) void wcombo(
    const float* __restrict__ Win, const float* __restrict__ Wdt,
    u16* __restrict__ outT, int KD,
    size_t winStride, size_t wdtStride, size_t outStride)
{
    __shared__ float wi[16][516];
    __shared__ float wd[512][16];
    const float* WinL = Win + (size_t)blockIdx.z * winStride;
    const float* WdtL = Wdt + (size_t)blockIdx.z * wdtStride;
    u16* outL = outT + (size_t)blockIdx.z * outStride;
    const int k0 = blockIdx.x * 16, n0 = blockIdx.y * 16;
    const int tid = threadIdx.x;
    for (int i = tid; i < 16 * 128; i += 256) {
        int r = i >> 7, c = i & 127;
        *(float4*)&wi[r][c * 4] =
            *(const float4*)&WinL[(size_t)(k0 + r) * DMODEL + c * 4];
    }
    for (int i = tid; i < 512 * 4; i += 256) {
        int j = i >> 2, c = i & 3;
        *(float4*)&wd[j][c * 4] =
            *(const float4*)&WdtL[(size_t)j * DMODEL + n0 + c * 4];
    }
    __syncthreads();
    const int kk = tid & 15, nn = tid >> 4;
    float acc = 0.f;
#pragma unroll 8
    for (int j = 0; j < 512; ++j)
        acc = fmaf(wi[kk][j], wd[j][nn], acc);
    outL[(size_t)(n0 + nn) * KD + k0 + kk] = f2bf(acc);
}

// ---------------------------------------------------------------------------
// biascat[0:512) = b_in; biascat[512+n] = b_dt[n] + sum_j b_in[j]*W_dt[j][n]
// z batched with strides.
// ---------------------------------------------------------------------------
__global__ __launch_bounds__(256) void biasprep(
    const float* __restrict__ bin, const float* __restrict__ Wdt,
    const float* __restrict__ bdt, float* __restrict__ biascat,
    size_t binStride, size_t wdtStride, size_t bdtStride, size_t outStride)
{
    const float* binL = bin + (size_t)blockIdx.z * binStride;
    const float* WdtL = Wdt + (size_t)blockIdx.z * wdtStride;
    const float* bdtL = bdt + (size_t)blockIdx.z * bdtStride;
    float* outL = biascat + (size_t)blockIdx.z * outStride;
    int idx = blockIdx.x * 256 + threadIdx.x;
    if (idx < DMODEL) { outL[idx] = binL[idx]; return; }
    int n = idx - DMODEL;
    float acc = bdtL[n];
    for (int j = 0; j < DMODEL; ++j)
        acc = fmaf(binL[j], WdtL[(size_t)j * DMODEL + n], acc);
    outL[idx] = acc;
}

// x -> bf16 cast
__global__ __launch_bounds__(256) void castx(
    const float* __restrict__ x, u16* __restrict__ xb, int n4)
{
    int i = blockIdx.x * 256 + threadIdx.x;
    if (i < n4) {
        float4 v = ((const float4*)x)[i];
        ushort4 o;
        o.x = f2bf(v.x); o.y = f2bf(v.y); o.z = f2bf(v.z); o.w = f2bf(v.w);
        ((ushort4*)xb)[i] = o;
    }
}

// ---------------------------------------------------------------------------
// Pack W_B,W_C ([L][512][16] f32) -> WBCT [L][32][512] bf16 (transposed).
// ---------------------------------------------------------------------------
__global__ __launch_bounds__(256) void prep_wbc(
    const float* __restrict__ WB, const float* __restrict__ WC,
    u16* __restrict__ WBCT)
{
    int idx = blockIdx.x * 256 + threadIdx.x;      // over NLAYERS*32*512
    int l = idx >> 14;                             // 32*512 = 16384
    int r = idx & 16383;
    int n = r >> 9, k = r & 511;
    float v = (n < 16) ? WB[((size_t)l * DMODEL + k) * DSTATE + n]
                       : WC[((size_t)l * DMODEL + k) * DSTATE + (n - 16)];
    WBCT[((size_t)l * 32 + n) * DMODEL + k] = f2bf(v);
}

// ---------------------------------------------------------------------------
// MFMA B/C projection: Bo/Co[M,16](f32) = u[M,512](bf16) @ {W_B,W_C}.
// ---------------------------------------------------------------------------
__global__ __launch_bounds__(256) void gemm_bc_mfma(
    const u16* __restrict__ A, const u16* __restrict__ WBCT,
    float* __restrict__ Bo, float* __restrict__ Co)
{
    const int tid = threadIdx.x;
    const int wv = tid >> 6, ln = tid & 63;
    const int m0 = blockIdx.x * 64 + wv * 16;
    const int g = ln >> 4, lm = ln & 15;

    f32x4 accB = (f32x4){0.f, 0.f, 0.f, 0.f};
    f32x4 accC = (f32x4){0.f, 0.f, 0.f, 0.f};
    const u16* arow = A + (size_t)(m0 + lm) * DMODEL;
    const u16* wb = WBCT + (size_t)lm * DMODEL;
    const u16* wc = WBCT + (size_t)(lm + 16) * DMODEL;
#pragma unroll
    for (int ks = 0; ks < DMODEL / 32; ++ks) {
        int ko = ks * 32 + g * 8;
        bf16x8 a = *(const bf16x8*)&arow[ko];
        bf16x8 b = *(const bf16x8*)&wb[ko];
        bf16x8 c = *(const bf16x8*)&wc[ko];
        accB = __builtin_amdgcn_mfma_f32_16x16x32_bf16(a, b, accB, 0, 0, 0);
        accC = __builtin_amdgcn_mfma_f32_16x16x32_bf16(a, c, accC, 0, 0, 0);
    }
#pragma unroll
    for (int r = 0; r < 4; ++r) {
        int m = m0 + g * 4 + r;
        Bo[(size_t)m * DSTATE + lm] = accB[r];
        Co[(size_t)m * DSTATE + lm] = accC[r];
    }
}

// ---------------------------------------------------------------------------
// Scan pass 1 (fast geometric path; fallback 16-exp loop).
// ---------------------------------------------------------------------------
__global__ __launch_bounds__(256) void scan_pass1(
    const u16* __restrict__ u, const u16* __restrict__ dt,
    const float* __restrict__ Bm, const float* __restrict__ A_log,
    float* __restrict__ P, float* __restrict__ S)
{
    const int tid = threadIdx.x;
    const int d = blockIdx.x * 256 + tid;
    const int c = blockIdx.y, b = blockIdx.z;
    __shared__ float Bs[TCH][DSTATE];

    const float* Bsrc = Bm + ((size_t)b * L_SZ + (size_t)c * TCH) * DSTATE;
    for (int i = tid; i < TCH * DSTATE / 4; i += 256)
        ((float4*)Bs)[i] = ((const float4*)Bsrc)[i];

    float Ac[16];
#pragma unroll
    for (int n = 0; n < 16; ++n) Ac[n] = -__expf(A_log[d * DSTATE + n]);
    bool geo = true;
#pragma unroll
    for (int n = 1; n < 16; ++n)
        geo &= fabsf(Ac[n] - (n + 1) * Ac[0]) <= 1e-4f * (n + 1) * fabsf(Ac[0]);
    __syncthreads();

    float s[16];
#pragma unroll
    for (int n = 0; n < 16; ++n) s[n] = 0.f;

    const size_t base = ((size_t)b * L_SZ + (size_t)c * TCH) * DMODEL + d;
    size_t o = (((size_t)b * NC + c) * DMODEL + d) * DSTATE;

    if (geo) {
        const float cK = Ac[0] * LOG2E;
        float qp = 1.f;
#pragma unroll 2
        for (int t = 0; t < TCH; ++t) {
            float dtv = bf2f(dt[base + (size_t)t * DMODEL]);
            float uv  = bf2f(u [base + (size_t)t * DMODEL]);
            float du = dtv * uv;
            float q = exp2f(dtv * cK);
            qp *= q;
            float a_[16];
            pow16(q, a_);
#pragma unroll
            for (int n = 0; n < 16; ++n)
                s[n] = fmaf(a_[n], s[n], du * Bs[t][n]);
        }
        float p_[16];
        pow16(qp, p_);
#pragma unroll
        for (int n = 0; n < 16; ++n) { P[o + n] = p_[n]; S[o + n] = s[n]; }
    } else {
        float p[16];
#pragma unroll
        for (int n = 0; n < 16; ++n) p[n] = 1.f;
#pragma unroll 2
        for (int t = 0; t < TCH; ++t) {
            float dtv = bf2f(dt[base + (size_t)t * DMODEL]);
            float uv  = bf2f(u [base + (size_t)t * DMODEL]);
            float du = dtv * uv;
#pragma unroll
            for (int n = 0; n < 16; ++n) {
                float a = __expf(dtv * Ac[n]);
                p[n] *= a;
                s[n] = fmaf(a, s[n], du * Bs[t][n]);
            }
        }
#pragma unroll
        for (int n = 0; n < 16; ++n) { P[o + n] = p[n]; S[o + n] = s[n]; }
    }
}

// ---------------------------------------------------------------------------
// Chunk fix-up: sequential over NC chunks per (b,d,n).
// ---------------------------------------------------------------------------
__global__ __launch_bounds__(256) void scan_fix(
    const float* __restrict__ P, const float* __restrict__ S,
    float* __restrict__ H0)
{
    const int idx = blockIdx.x * 256 + threadIdx.x;   // over B*D*N
    const int dn = idx & (DMODEL * DSTATE - 1);
    const int b = idx >> 13;                          // D*N = 8192
    float h = 0.f;
#pragma unroll
    for (int c = 0; c < NC; ++c) {
        size_t o = (((size_t)b * NC + c) << 13) + dn;
        H0[o] = h;
        h = fmaf(P[o], h, S[o]);
    }
}

// ---------------------------------------------------------------------------
// Scan pass 2: seeded with H0; emit y bf16 (+ fp32 last-token row).
// ---------------------------------------------------------------------------
__global__ __launch_bounds__(256) void scan_pass2(
    const u16* __restrict__ u, const u16* __restrict__ dt,
    const float* __restrict__ Bm, const float* __restrict__ Cm,
    const float* __restrict__ A_log, const float* __restrict__ Dskip,
    const float* __restrict__ H0, u16* __restrict__ yb,
    float* __restrict__ ylast)
{
    const int tid = threadIdx.x;
    const int d = blockIdx.x * 256 + tid;
    const int c = blockIdx.y, b = blockIdx.z;
    __shared__ float Bs[TCH][DSTATE];
    __shared__ float Cs[TCH][DSTATE];

    const float* Bsrc = Bm + ((size_t)b * L_SZ + (size_t)c * TCH) * DSTATE;
    const float* Csrc = Cm + ((size_t)b * L_SZ + (size_t)c * TCH) * DSTATE;
    for (int i = tid; i < TCH * DSTATE / 4; i += 256) {
        ((float4*)Bs)[i] = ((const float4*)Bsrc)[i];
        ((float4*)Cs)[i] = ((const float4*)Csrc)[i];
    }

    float Ac[16];
#pragma unroll
    for (int n = 0; n < 16; ++n) Ac[n] = -__expf(A_log[d * DSTATE + n]);
    bool geo = true;
#pragma unroll
    for (int n = 1; n < 16; ++n)
        geo &= fabsf(Ac[n] - (n + 1) * Ac[0]) <= 1e-4f * (n + 1) * fabsf(Ac[0]);
    const float Dk = Dskip[d];

    float h[16];
    size_t ho = (((size_t)b * NC + c) * DMODEL + d) * DSTATE;
#pragma unroll
    for (int n = 0; n < 16; ++n) h[n] = H0[ho + n];
    __syncthreads();

    const size_t base = ((size_t)b * L_SZ + (size_t)c * TCH) * DMODEL + d;

    if (geo) {
        const float cK = Ac[0] * LOG2E;
#pragma unroll 2
        for (int t = 0; t < TCH; ++t) {
            float dtv = bf2f(dt[base + (size_t)t * DMODEL]);
            float uv  = bf2f(u [base + (size_t)t * DMODEL]);
            float du = dtv * uv;
            float q = exp2f(dtv * cK);
            float a_[16];
            pow16(q, a_);
            float yv = 0.f;
#pragma unroll
            for (int n = 0; n < 16; ++n) {
                h[n] = fmaf(a_[n], h[n], du * Bs[t][n]);
                yv = fmaf(h[n], Cs[t][n], yv);
            }
            yv = fmaf(uv, Dk, yv);
            yb[base + (size_t)t * DMODEL] = f2bf(yv);
            if (c == NC - 1 && t == TCH - 1) ylast[(size_t)b * DMODEL + d] = yv;
        }
    } else {
#pragma unroll 2
        for (int t = 0; t < TCH; ++t) {
            float dtv = bf2f(dt[base + (size_t)t * DMODEL]);
            float uv  = bf2f(u [base + (size_t)t * DMODEL]);
            float du = dtv * uv;
            float yv = 0.f;
#pragma unroll
            for (int n = 0; n < 16; ++n) {
                float a = __expf(dtv * Ac[n]);
                h[n] = fmaf(a, h[n], du * Bs[t][n]);
                yv = fmaf(h[n], Cs[t][n], yv);
            }
            yv = fmaf(uv, Dk, yv);
            yb[base + (size_t)t * DMODEL] = f2bf(yv);
            if (c == NC - 1 && t == TCH - 1) ylast[(size_t)b * DMODEL + d] = yv;
        }
    }
}

// ---------------------------------------------------------------------------
// LayerNorm(last token) + head. One block per batch.
// ---------------------------------------------------------------------------
__global__ __launch_bounds__(256) void ln_head_kernel(
    const float* __restrict__ ylast, const float* __restrict__ g,
    const float* __restrict__ bb, const float* __restrict__ hw,
    const float* __restrict__ hb, float* __restrict__ out)
{
    const int b = blockIdx.x;
    const int tid = threadIdx.x;
    const float* row = ylast + (size_t)b * DMODEL;
    float v0 = row[tid], v1 = row[tid + 256];
    float s = v0 + v1;
    float s2 = v0 * v0 + v1 * v1;
#pragma unroll
    for (int o = 32; o >= 1; o >>= 1) {
        s += __shfl_xor(s, o);
        s2 += __shfl_xor(s2, o);
    }
    __shared__ float red[8];
    const int w = tid >> 6;
    if ((tid & 63) == 0) { red[w] = s; red[4 + w] = s2; }
    __syncthreads();
    s = red[0] + red[1] + red[2] + red[3];
    s2 = red[4] + red[5] + red[6] + red[7];
    float mu = s * (1.f / DMODEL);
    float var = s2 * (1.f / DMODEL) - mu * mu;
    float r = rsqrtf(var + LN_EPS);
    float c = ((v0 - mu) * r * g[tid] + bb[tid]) * hw[tid]
            + ((v1 - mu) * r * g[tid + 256] + bb[tid + 256]) * hw[tid + 256];
#pragma unroll
    for (int o = 32; o >= 1; o >>= 1) c += __shfl_xor(c, o);
    __syncthreads();
    if ((tid & 63) == 0) red[w] = c;
    __syncthreads();
    if (tid == 0) out[b] = red[0] + red[1] + red[2] + red[3] + hb[0];
}

// ---------------------------------------------------------------------------
extern "C" void kernel_launch(void* const* d_in, const int* in_sizes, int n_in,
                              void* d_out, int out_size, void* d_ws, size_t ws_size,
                              hipStream_t stream)
{
    const float* x      = (const float*)d_in[0];
    const float* W_in0  = (const float*)d_in[1];
    const float* b_in0  = (const float*)d_in[2];
    const float* W_in   = (const float*)d_in[3];
    const float* b_in   = (const float*)d_in[4];
    const float* A_log  = (const float*)d_in[5];
    const float* D_skip = (const float*)d_in[6];
    const float* W_dt   = (const float*)d_in[7];
    const float* b_dt   = (const float*)d_in[8];
    const float* W_B    = (const float*)d_in[9];
    const float* W_C    = (const float*)d_in[10];
    const float* ln_g   = (const float*)d_in[11];
    const float* ln_b   = (const float*)d_in[12];
    const float* head_w = (const float*)d_in[13];
    const float* head_b = (const float*)d_in[14];
    float* out = (float*)d_out;

    const size_t BLD = (size_t)B_SZ * L_SZ * DMODEL;         // 16.78M
    const size_t BLN = (size_t)B_SZ * L_SZ * DSTATE;         // 0.52M
    const size_t BCD = (size_t)B_SZ * NC * DMODEL * DSTATE;  // 4.19M
    const size_t XBN = (size_t)B_SZ * L_SZ * DIN;            // 2.10M

    float* fp = (float*)d_ws;
    float* Bbuf  = fp; fp += BLN;
    float* Cbuf  = fp; fp += BLN;
    float* Pbuf  = fp; fp += BCD;
    float* Sbuf  = fp; fp += BCD;
    float* H0buf = fp; fp += BCD;
    float* ylast = fp; fp += (size_t)B_SZ * DMODEL;
    float* biascat = fp; fp += (size_t)NLAYERS * NFUSED;
    u16* hp = (u16*)fp;
    u16* xb    = hp; hp += XBN;
    u16* ub    = hp; hp += BLD;
    u16* dtb   = hp; hp += BLD;
    u16* ybuf  = hp; hp += BLD;
    u16* BT0   = hp; hp += (size_t)NFUSED * DIN;                    // layer 0
    u16* BTcat = hp; hp += (size_t)(NLAYERS - 1) * NFUSED * DMODEL; // layers 1-3
    u16* WBCT  = hp; hp += (size_t)NLAYERS * 32 * DMODEL;

    const int M = B_SZ * L_SZ;   // 32768

    // ---- prep ----
    castx<<<(XBN / 4 + 255) / 256, 256, 0, stream>>>(x, xb, XBN / 4);
    prep_wbc<<<(NLAYERS * 32 * DMODEL) / 256, 256, 0, stream>>>(W_B, W_C, WBCT);
    // layer 0: BT0 = [W_in0^T | (W_in0@W_dt0)^T]  (1024 rows, K=64)
    wtrans<<<dim3(DIN / 32, DMODEL / 32, 1), 256, 0, stream>>>(
        W_in0, BT0, DIN, DMODEL, 0, 0);
    wcombo<<<dim3(DIN / 16, DMODEL / 16, 1), 256, 0, stream>>>(
        W_in0, W_dt, BT0 + (size_t)DMODEL * DIN, DIN, 0, 0, 0);
    biasprep<<<dim3(4, 1, 1), 256, 0, stream>>>(
        b_in0, W_dt, b_dt, biascat, 0, 0, 0, 0);
    // layers 1-3 batched over z
    wtrans<<<dim3(DMODEL / 32, DMODEL / 32, NLAYERS - 1), 256, 0, stream>>>(
        W_in, BTcat, DMODEL, DMODEL,
        (size_t)DMODEL * DMODEL, (size_t)NFUSED * DMODEL);
    wcombo<<<dim3(DMODEL / 16, DMODEL / 16, NLAYERS - 1), 256, 0, stream>>>(
        W_in, W_dt + (size_t)DMODEL * DMODEL,
        BTcat + (size_t)DMODEL * DMODEL, DMODEL,
        (size_t)DMODEL * DMODEL, (size_t)DMODEL * DMODEL,
        (size_t)NFUSED * DMODEL);
    biasprep<<<dim3(4, 1, NLAYERS - 1), 256, 0, stream>>>(
        b_in, W_dt + (size_t)DMODEL * DMODEL, b_dt + DMODEL, biascat + NFUSED,
        DMODEL, (size_t)DMODEL * DMODEL, DMODEL, NFUSED);

    // ---- layers ----
    for (int l = 0; l < NLAYERS; ++l) {
        if (l == 0) {
            gemm_fused<DIN><<<(M / 128) * (NFUSED / 128), 512, 0, stream>>>(
                xb, BT0, biascat, ub, dtb, M);
        } else {
            gemm_fused<DMODEL><<<(M / 128) * (NFUSED / 128), 512, 0, stream>>>(
                ybuf, BTcat + (size_t)(l - 1) * NFUSED * DMODEL,
                biascat + (size_t)l * NFUSED, ub, dtb, M);
        }
        gemm_bc_mfma<<<M / 64, 256, 0, stream>>>(
            ub, WBCT + (size_t)l * 32 * DMODEL, Bbuf, Cbuf);
        const float* Al = A_log + (size_t)l * DMODEL * DSTATE;
        scan_pass1<<<dim3(DMODEL / 256, NC, B_SZ), 256, 0, stream>>>(
            ub, dtb, Bbuf, Al, Pbuf, Sbuf);
        scan_fix<<<(B_SZ * DMODEL * DSTATE) / 256, 256, 0, stream>>>(
            Pbuf, Sbuf, H0buf);
        scan_pass2<<<dim3(DMODEL / 256, NC, B_SZ), 256, 0, stream>>>(
            ub, dtb, Bbuf, Cbuf, Al, D_skip + (size_t)l * DMODEL,
            H0buf, ybuf, ylast);
    }

    ln_head_kernel<<<B_SZ, 256, 0, stream>>>(ylast, ln_g, ln_b, head_w, head_b, out);
}